// Round 4
// baseline (1598.316 us; speedup 1.0000x reference)
//
#include <hip/hip_runtime.h>
#include <hip/hip_bf16.h>
#include <cstddef>

#define D_MODEL 1024
#define NHEAD   16
#define HD      64
#define BATCH   2
#define SEQ     2048
#define BH      (BATCH*NHEAD)   // 32

// ---------------------------------------------------------------------------
// K1: qkv = x @ w_qkv  (M=4096, K=1024, N=3072), scatter into Q/K/V (BH,S,HD)
// 128x128 tile, 256 threads, 8x8 microtile, BK=8, fp32 vector ALU.
// ---------------------------------------------------------------------------
__global__ __launch_bounds__(256) void gemm_qkv_kernel(
    const float* __restrict__ X, const float* __restrict__ W,
    float* __restrict__ Qo, float* __restrict__ Ko, float* __restrict__ Vo)
{
    const int KDIM = D_MODEL;     // 1024
    const int N    = 3*D_MODEL;   // 3072
    __shared__ float As[8][128];
    __shared__ float Bs[8][128];
    const int tid  = threadIdx.x;
    const int tx   = tid & 15;
    const int ty   = tid >> 4;
    const int row0 = blockIdx.y * 128;
    const int col0 = blockIdx.x * 128;
    const int a_row = tid >> 1;
    const int a_col = (tid & 1) << 2;
    const int b_row = tid >> 5;
    const int b_col = (tid & 31) << 2;
    float acc[8][8] = {};
    for (int k0 = 0; k0 < KDIM; k0 += 8) {
        float4 av = *(const float4*)&X[(size_t)(row0 + a_row)*KDIM + k0 + a_col];
        float4 bv = *(const float4*)&W[(size_t)(k0 + b_row)*N + col0 + b_col];
        As[a_col+0][a_row] = av.x;
        As[a_col+1][a_row] = av.y;
        As[a_col+2][a_row] = av.z;
        As[a_col+3][a_row] = av.w;
        *(float4*)&Bs[b_row][b_col] = bv;
        __syncthreads();
        #pragma unroll
        for (int k = 0; k < 8; ++k) {
            float a[8], b[8];
            *(float4*)&a[0] = *(const float4*)&As[k][ty*8];
            *(float4*)&a[4] = *(const float4*)&As[k][ty*8+4];
            *(float4*)&b[0] = *(const float4*)&Bs[k][tx*8];
            *(float4*)&b[4] = *(const float4*)&Bs[k][tx*8+4];
            #pragma unroll
            for (int i = 0; i < 8; ++i)
                #pragma unroll
                for (int j = 0; j < 8; ++j)
                    acc[i][j] = fmaf(a[i], b[j], acc[i][j]);
        }
        __syncthreads();
    }
    const int cbase = col0 + tx*8;
    const int which = cbase >> 10;
    const int rem   = cbase & 1023;
    const int h     = rem >> 6;
    const int dd    = rem & 63;
    float* dstBase = (which == 0) ? Qo : (which == 1) ? Ko : Vo;
    #pragma unroll
    for (int i = 0; i < 8; ++i) {
        const int r  = row0 + ty*8 + i;
        const int bb = r >> 11;        // batch
        const int ss = r & 2047;       // seq pos
        float* dst = dstBase + ((size_t)(bb*NHEAD + h)*SEQ + ss)*HD + dd;
        *(float4*)&dst[0] = make_float4(acc[i][0], acc[i][1], acc[i][2], acc[i][3]);
        *(float4*)&dst[4] = make_float4(acc[i][4], acc[i][5], acc[i][6], acc[i][7]);
    }
}

// ---------------------------------------------------------------------------
// K2 v3: causal flash attention, fp32, HD split 4-ways across lanes.
// Block = 256 threads = 64 query rows of one (b,h). Lane: ds=lane&3 owns
// dims [16ds,16ds+16), rl=lane>>2 is row-in-wave. QK dot reduced across the
// 4-lane group via shfl_xor(1),shfl_xor(2). K/V tiles of 32 keys in LDS.
// __launch_bounds__(256,2): VGPR cap 256 so q[16]+o[16]+s[32]+temps (~110
// VGPR) does NOT spill (round-2's (256,4) clamped to 64 VGPR -> 515 MB of
// scratch writes per dispatch). ~110 VGPR still fits 4 waves/SIMD.
// ---------------------------------------------------------------------------
__global__ __launch_bounds__(256, 2) void attn_kernel(
    const float* __restrict__ Q, const float* __restrict__ K,
    const float* __restrict__ V, float* __restrict__ AO)
{
    __shared__ float Ks[32*64];
    __shared__ float Vs[32*64];
    const int tid  = threadIdx.x;
    const int lane = tid & 63;
    const int wv   = tid >> 6;            // wave 0..3
    const int ds   = lane & 3;            // dim split
    const int rl   = lane >> 2;           // row in wave 0..15
    const int bh   = blockIdx.y;          // 0..31
    const int qt   = blockIdx.x;          // 64-row q tile, 0..31
    const int row  = qt*64 + wv*16 + rl;  // query row
    const int d0   = ds*16;

    const float* qp = Q + ((size_t)bh*SEQ + row)*HD + d0;
    float q[16];
    #pragma unroll
    for (int i = 0; i < 4; ++i)
        *(float4*)&q[i*4] = *(const float4*)&qp[i*4];
    float o[16];
    #pragma unroll
    for (int i = 0; i < 16; ++i) o[i] = 0.f;
    float m = -1e30f, l = 0.f;

    const int kend = qt*64 + 64;
    const int wave_max_row = qt*64 + wv*16 + 15;

    for (int kt = 0; kt < kend; kt += 32) {
        __syncthreads();                  // protect previous tile reads
        const float* ksrc = K + ((size_t)bh*SEQ + kt)*HD;
        const float* vsrc = V + ((size_t)bh*SEQ + kt)*HD;
        *(float4*)&Ks[tid*4]        = *(const float4*)&ksrc[tid*4];
        *(float4*)&Ks[1024 + tid*4] = *(const float4*)&ksrc[1024 + tid*4];
        *(float4*)&Vs[tid*4]        = *(const float4*)&vsrc[tid*4];
        *(float4*)&Vs[1024 + tid*4] = *(const float4*)&vsrc[1024 + tid*4];
        __syncthreads();
        if (kt > wave_max_row) continue;  // whole wave above diagonal; all
                                          // threads still reach top barrier
        float s[32];
        #pragma unroll
        for (int kk = 0; kk < 32; ++kk) {
            const float* kp = &Ks[kk*64 + d0];
            float s0 = 0.f, s1 = 0.f, s2 = 0.f, s3 = 0.f;
            #pragma unroll
            for (int i = 0; i < 4; ++i) {
                float4 k4 = *(const float4*)&kp[i*4];
                s0 = fmaf(k4.x, q[i*4+0], s0);
                s1 = fmaf(k4.y, q[i*4+1], s1);
                s2 = fmaf(k4.z, q[i*4+2], s2);
                s3 = fmaf(k4.w, q[i*4+3], s3);
            }
            float p = (s0+s1)+(s2+s3);
            p += __shfl_xor(p, 1);
            p += __shfl_xor(p, 2);        // all 4 lanes now hold full dot
            float sv = p * 0.125f;
            s[kk] = (kt + kk > row) ? -1e30f : sv;
        }
        float mt = s[0];
        #pragma unroll
        for (int kk = 1; kk < 32; ++kk) mt = fmaxf(mt, s[kk]);
        const float mnew  = fmaxf(m, mt);
        const float alpha = __expf(m - mnew);
        float psum = 0.f;
        #pragma unroll
        for (int kk = 0; kk < 32; ++kk) { s[kk] = __expf(s[kk]-mnew); psum += s[kk]; }
        l = l*alpha + psum;
        m = mnew;
        #pragma unroll
        for (int i = 0; i < 16; ++i) o[i] *= alpha;
        #pragma unroll
        for (int kk = 0; kk < 32; ++kk) {
            const float* vp = &Vs[kk*64 + d0];
            const float p = s[kk];
            #pragma unroll
            for (int i = 0; i < 4; ++i) {
                float4 v4 = *(const float4*)&vp[i*4];
                o[i*4+0] = fmaf(p, v4.x, o[i*4+0]);
                o[i*4+1] = fmaf(p, v4.y, o[i*4+1]);
                o[i*4+2] = fmaf(p, v4.z, o[i*4+2]);
                o[i*4+3] = fmaf(p, v4.w, o[i*4+3]);
            }
        }
    }
    const float inv = 1.f / l;
    const int bb = bh >> 4;
    const int h  = bh & 15;
    float* dst = AO + ((size_t)bb*SEQ + row)*D_MODEL + h*HD + d0;
    #pragma unroll
    for (int i = 0; i < 4; ++i)
        *(float4*)&dst[i*4] = make_float4(o[i*4+0]*inv, o[i*4+1]*inv,
                                          o[i*4+2]*inv, o[i*4+3]*inv);
}

// ---------------------------------------------------------------------------
// K3: out = AO @ w_out  (M=4096, K=1024, N=1024)
// ---------------------------------------------------------------------------
__global__ __launch_bounds__(256) void gemm_out_kernel(
    const float* __restrict__ A, const float* __restrict__ W,
    float* __restrict__ C)
{
    const int KDIM = D_MODEL;   // 1024
    const int N    = D_MODEL;   // 1024
    __shared__ float As[8][128];
    __shared__ float Bs[8][128];
    const int tid  = threadIdx.x;
    const int tx   = tid & 15;
    const int ty   = tid >> 4;
    const int row0 = blockIdx.y * 128;
    const int col0 = blockIdx.x * 128;
    const int a_row = tid >> 1;
    const int a_col = (tid & 1) << 2;
    const int b_row = tid >> 5;
    const int b_col = (tid & 31) << 2;
    float acc[8][8] = {};
    for (int k0 = 0; k0 < KDIM; k0 += 8) {
        float4 av = *(const float4*)&A[(size_t)(row0 + a_row)*KDIM + k0 + a_col];
        float4 bv = *(const float4*)&W[(size_t)(k0 + b_row)*N + col0 + b_col];
        As[a_col+0][a_row] = av.x;
        As[a_col+1][a_row] = av.y;
        As[a_col+2][a_row] = av.z;
        As[a_col+3][a_row] = av.w;
        *(float4*)&Bs[b_row][b_col] = bv;
        __syncthreads();
        #pragma unroll
        for (int k = 0; k < 8; ++k) {
            float a[8], b[8];
            *(float4*)&a[0] = *(const float4*)&As[k][ty*8];
            *(float4*)&a[4] = *(const float4*)&As[k][ty*8+4];
            *(float4*)&b[0] = *(const float4*)&Bs[k][tx*8];
            *(float4*)&b[4] = *(const float4*)&Bs[k][tx*8+4];
            #pragma unroll
            for (int i = 0; i < 8; ++i)
                #pragma unroll
                for (int j = 0; j < 8; ++j)
                    acc[i][j] = fmaf(a[i], b[j], acc[i][j]);
        }
        __syncthreads();
    }
    #pragma unroll
    for (int i = 0; i < 8; ++i) {
        const int r = row0 + ty*8 + i;
        float* dst = C + (size_t)r*N + col0 + tx*8;
        *(float4*)&dst[0] = make_float4(acc[i][0], acc[i][1], acc[i][2], acc[i][3]);
        *(float4*)&dst[4] = make_float4(acc[i][4], acc[i][5], acc[i][6], acc[i][7]);
    }
}

// ---------------------------------------------------------------------------
extern "C" void kernel_launch(void* const* d_in, const int* in_sizes, int n_in,
                              void* d_out, int out_size, void* d_ws, size_t ws_size,
                              hipStream_t stream)
{
    const float* x     = (const float*)d_in[0];   // (2,2048,1024)
    const float* w_qkv = (const float*)d_in[1];   // (1024,3072)
    const float* w_out = (const float*)d_in[2];   // (1024,1024)
    float* out = (float*)d_out;                   // (2,2048,1024)

    const size_t per = (size_t)BH * SEQ * HD;     // 4,194,304 floats
    float* Q  = (float*)d_ws;
    float* K  = Q + per;
    float* V  = K + per;
    float* AO = V + per;                          // (B,S,D) attn output

    // qkv projection: grid = (N/128, M/128) = (24, 32)
    gemm_qkv_kernel<<<dim3(24, 32), 256, 0, stream>>>(x, w_qkv, Q, K, V);
    // causal attention: grid = (S/64, B*H) = (32, 32)
    attn_kernel<<<dim3(SEQ/64, BH), 256, 0, stream>>>(Q, K, V, AO);
    // output projection: grid = (N/128, M/128) = (8, 32)
    gemm_out_kernel<<<dim3(8, 32), 256, 0, stream>>>(AO, w_out, out);
}

// Round 9
// 639.493 us; speedup vs baseline: 2.4993x; 2.4993x over previous
//
#include <hip/hip_runtime.h>
#include <hip/hip_bf16.h>
#include <cstddef>

#define D_MODEL 1024
#define NHEAD   16
#define HD      64
#define BATCH   2
#define SEQ     2048
#define BH      (BATCH*NHEAD)   // 32

typedef short bf16x8 __attribute__((ext_vector_type(8)));
typedef float f32x4  __attribute__((ext_vector_type(4)));

static __device__ __forceinline__ unsigned short f2bf(float f) {
    __hip_bfloat16 h = __float2bfloat16(f);   // RNE
    return __builtin_bit_cast(unsigned short, h);
}
static __device__ __forceinline__ unsigned int pk2(float a, float b) {
    return (unsigned int)f2bf(a) | ((unsigned int)f2bf(b) << 16);
}

// ---------------------------------------------------------------------------
// K1: qkv = x @ w_qkv  (M=4096, K=1024, N=3072). fp32 compute (vector ALU),
// epilogue converts to bf16 and scatters into Qb/Kb/Vb (BH,S,64) for MFMA attn.
// ---------------------------------------------------------------------------
__global__ __launch_bounds__(256) void gemm_qkv_kernel(
    const float* __restrict__ X, const float* __restrict__ W,
    unsigned short* __restrict__ Qo, unsigned short* __restrict__ Ko,
    unsigned short* __restrict__ Vo)
{
    const int KDIM = D_MODEL;     // 1024
    const int N    = 3*D_MODEL;   // 3072
    __shared__ float As[8][128];
    __shared__ float Bs[8][128];
    const int tid  = threadIdx.x;
    const int tx   = tid & 15;
    const int ty   = tid >> 4;
    const int row0 = blockIdx.y * 128;
    const int col0 = blockIdx.x * 128;
    const int a_row = tid >> 1;
    const int a_col = (tid & 1) << 2;
    const int b_row = tid >> 5;
    const int b_col = (tid & 31) << 2;
    float acc[8][8] = {};
    for (int k0 = 0; k0 < KDIM; k0 += 8) {
        float4 av = *(const float4*)&X[(size_t)(row0 + a_row)*KDIM + k0 + a_col];
        float4 bv = *(const float4*)&W[(size_t)(k0 + b_row)*N + col0 + b_col];
        As[a_col+0][a_row] = av.x;
        As[a_col+1][a_row] = av.y;
        As[a_col+2][a_row] = av.z;
        As[a_col+3][a_row] = av.w;
        *(float4*)&Bs[b_row][b_col] = bv;
        __syncthreads();
        #pragma unroll
        for (int k = 0; k < 8; ++k) {
            float a[8], b[8];
            *(float4*)&a[0] = *(const float4*)&As[k][ty*8];
            *(float4*)&a[4] = *(const float4*)&As[k][ty*8+4];
            *(float4*)&b[0] = *(const float4*)&Bs[k][tx*8];
            *(float4*)&b[4] = *(const float4*)&Bs[k][tx*8+4];
            #pragma unroll
            for (int i = 0; i < 8; ++i)
                #pragma unroll
                for (int j = 0; j < 8; ++j)
                    acc[i][j] = fmaf(a[i], b[j], acc[i][j]);
        }
        __syncthreads();
    }
    const int cbase = col0 + tx*8;
    const int which = cbase >> 10;
    const int rem   = cbase & 1023;
    const int h     = rem >> 6;
    const int dd    = rem & 63;
    unsigned short* dstBase = (which == 0) ? Qo : (which == 1) ? Ko : Vo;
    #pragma unroll
    for (int i = 0; i < 8; ++i) {
        const int r  = row0 + ty*8 + i;
        const int bb = r >> 11;        // batch
        const int ss = r & 2047;       // seq pos
        unsigned short* dst = dstBase + ((size_t)(bb*NHEAD + h)*SEQ + ss)*HD + dd;
        uint4 w;
        w.x = pk2(acc[i][0], acc[i][1]);
        w.y = pk2(acc[i][2], acc[i][3]);
        w.z = pk2(acc[i][4], acc[i][5]);
        w.w = pk2(acc[i][6], acc[i][7]);
        *(uint4*)dst = w;
    }
}

// ---------------------------------------------------------------------------
// K2 v5: causal flash attention, bf16 MFMA (16x16x32).
// Block = 4 waves x 16 q-rows = 64 rows of one (b,h). KV tiles of 32 keys,
// double-buffered LDS, 1 barrier/tile. Layouts (guide-verified m89):
//   A(16x32): lane = m + 16*(k>>3), 8 consecutive k per lane
//   B(32x16): lane = n + 16*(k>>3), 8 consecutive k per lane
//   C/D:      col = lane&15, row = (lane>>4)*4 + reg
// BUGFIX vs v4: Ks rows hold 64 dims -> stride 72 shorts (v4 had 40 -> rows
// overlapped, dims >=40 garbage, absmax 1.62). 144B rows stay 16B-aligned.
// Vt rows hold 32 keys -> stride 40 is correct there.
// P (C-layout) -> per-wave LDS -> re-read in A-layout for PV.
// ---------------------------------------------------------------------------
__global__ __launch_bounds__(256, 2) void attn_kernel(
    const unsigned short* __restrict__ Qb, const unsigned short* __restrict__ Kb,
    const unsigned short* __restrict__ Vb, float* __restrict__ AO)
{
    __shared__ __align__(16) unsigned short Ks[2][32][72];  // keys x dims(+pad)
    __shared__ __align__(16) unsigned short Vt[2][64][40];  // dims x keys(+pad)
    __shared__ __align__(16) unsigned short Pl[4][16][32];  // per-wave P

    const int tid = threadIdx.x;
    const int wv  = tid >> 6;
    const int l   = tid & 63;
    const int ln  = l & 15;          // n / col within MFMA
    const int lg  = l >> 4;          // k-chunk group / row group
    const int bh  = blockIdx.y;
    const int qt  = 31 - blockIdx.x; // long blocks first
    const int qrow0 = qt*64 + wv*16; // this wave's 16 q-rows
    const int nT  = 2*qt + 2;        // number of 32-key tiles

    const unsigned short* Qbh = Qb + (size_t)bh*SEQ*HD;
    const unsigned short* Kbh = Kb + (size_t)bh*SEQ*HD;
    const unsigned short* Vbh = Vb + (size_t)bh*SEQ*HD;

    // Q fragments (A-layout): row = qrow0+ln, dims lg*8..+7 and 32+lg*8..+7
    const bf16x8 q0 = *(const bf16x8*)&Qbh[(size_t)(qrow0 + ln)*HD + lg*8];
    const bf16x8 q1 = *(const bf16x8*)&Qbh[(size_t)(qrow0 + ln)*HD + 32 + lg*8];

    f32x4 o[4] = {};
    float m[4], lsum[4];
    #pragma unroll
    for (int r = 0; r < 4; ++r) { m[r] = -1e30f; lsum[r] = 0.f; }

    // staging indices
    const int s_kl = tid >> 3;            // key for K stage
    const int s_d0 = (tid & 7) << 3;      // dim0 for K stage
    const int s_dg = tid >> 4;            // dim group for V stage
    const int s_kp = (tid & 15) << 1;     // key pair for V stage

    // ---- stage tile 0 into buf 0
    {
        const int kt = 0;
        *(uint4*)&Ks[0][s_kl][s_d0] = *(const uint4*)&Kbh[(size_t)(kt + s_kl)*HD + s_d0];
        uint2 va = *(const uint2*)&Vbh[(size_t)(kt + s_kp    )*HD + s_dg*4];
        uint2 vb = *(const uint2*)&Vbh[(size_t)(kt + s_kp + 1)*HD + s_dg*4];
        *(unsigned int*)&Vt[0][s_dg*4+0][s_kp] = (va.x & 0xffffu) | (vb.x << 16);
        *(unsigned int*)&Vt[0][s_dg*4+1][s_kp] = (va.x >> 16)     | (vb.x & 0xffff0000u);
        *(unsigned int*)&Vt[0][s_dg*4+2][s_kp] = (va.y & 0xffffu) | (vb.y << 16);
        *(unsigned int*)&Vt[0][s_dg*4+3][s_kp] = (va.y >> 16)     | (vb.y & 0xffff0000u);
    }

    for (int t = 0; t < nT; ++t) {
        __syncthreads();
        const int buf = t & 1;
        if (t + 1 < nT) {               // prefetch next tile into other buffer
            const int kt = (t + 1) * 32;
            const int nb = buf ^ 1;
            *(uint4*)&Ks[nb][s_kl][s_d0] = *(const uint4*)&Kbh[(size_t)(kt + s_kl)*HD + s_d0];
            uint2 va = *(const uint2*)&Vbh[(size_t)(kt + s_kp    )*HD + s_dg*4];
            uint2 vb = *(const uint2*)&Vbh[(size_t)(kt + s_kp + 1)*HD + s_dg*4];
            *(unsigned int*)&Vt[nb][s_dg*4+0][s_kp] = (va.x & 0xffffu) | (vb.x << 16);
            *(unsigned int*)&Vt[nb][s_dg*4+1][s_kp] = (va.x >> 16)     | (vb.x & 0xffff0000u);
            *(unsigned int*)&Vt[nb][s_dg*4+2][s_kp] = (va.y & 0xffffu) | (vb.y << 16);
            *(unsigned int*)&Vt[nb][s_dg*4+3][s_kp] = (va.y >> 16)     | (vb.y & 0xffff0000u);
        }
        const int kt = t * 32;
        if (kt > qrow0 + 15) continue;  // wave fully above diagonal (uniform)

        // ---- QK^T: S(16 x 32keys)
        bf16x8 k00 = *(const bf16x8*)&Ks[buf][ln     ][lg*8];
        bf16x8 k01 = *(const bf16x8*)&Ks[buf][ln     ][32 + lg*8];
        bf16x8 k10 = *(const bf16x8*)&Ks[buf][16 + ln][lg*8];
        bf16x8 k11 = *(const bf16x8*)&Ks[buf][16 + ln][32 + lg*8];
        f32x4 s0 = {}, s1 = {};
        s0 = __builtin_amdgcn_mfma_f32_16x16x32_bf16(q0, k00, s0, 0, 0, 0);
        s0 = __builtin_amdgcn_mfma_f32_16x16x32_bf16(q1, k01, s0, 0, 0, 0);
        s1 = __builtin_amdgcn_mfma_f32_16x16x32_bf16(q0, k10, s1, 0, 0, 0);
        s1 = __builtin_amdgcn_mfma_f32_16x16x32_bf16(q1, k11, s1, 0, 0, 0);

        // ---- scale + causal mask. row(reg r) = qrow0+lg*4+r, keys ln, 16+ln
        float mt[4];
        #pragma unroll
        for (int r = 0; r < 4; ++r) {
            const int qg = qrow0 + lg*4 + r;
            float a = s0[r] * 0.125f, b = s1[r] * 0.125f;
            a = (kt + ln      > qg) ? -1e30f : a;
            b = (kt + 16 + ln > qg) ? -1e30f : b;
            s0[r] = a; s1[r] = b;
            mt[r] = fmaxf(a, b);
        }
        // butterfly max over the 16 n-lanes (xor 1,2,4,8 stays in lg group)
        #pragma unroll
        for (int d = 1; d <= 8; d <<= 1) {
            #pragma unroll
            for (int r = 0; r < 4; ++r) mt[r] = fmaxf(mt[r], __shfl_xor(mt[r], d));
        }
        float alpha[4], ps[4];
        #pragma unroll
        for (int r = 0; r < 4; ++r) {
            const float mnew = fmaxf(m[r], mt[r]);
            alpha[r] = __expf(m[r] - mnew);
            m[r] = mnew;
            s0[r] = __expf(s0[r] - mnew);
            s1[r] = __expf(s1[r] - mnew);
            ps[r] = s0[r] + s1[r];
        }
        #pragma unroll
        for (int d = 1; d <= 8; d <<= 1) {
            #pragma unroll
            for (int r = 0; r < 4; ++r) ps[r] += __shfl_xor(ps[r], d);
        }
        #pragma unroll
        for (int r = 0; r < 4; ++r) {
            lsum[r] = lsum[r]*alpha[r] + ps[r];
            #pragma unroll
            for (int f = 0; f < 4; ++f) o[f][r] *= alpha[r];
        }

        // ---- P -> LDS (C-layout write), re-read as A-layout
        #pragma unroll
        for (int r = 0; r < 4; ++r) {
            Pl[wv][lg*4 + r][ln]      = f2bf(s0[r]);
            Pl[wv][lg*4 + r][16 + ln] = f2bf(s1[r]);
        }
        bf16x8 pa = *(const bf16x8*)&Pl[wv][ln][lg*8];

        // ---- PV: O(16 x 64) += P(16x32) * V(32x64)
        #pragma unroll
        for (int f = 0; f < 4; ++f) {
            bf16x8 vf = *(const bf16x8*)&Vt[buf][f*16 + ln][lg*8];
            o[f] = __builtin_amdgcn_mfma_f32_16x16x32_bf16(pa, vf, o[f], 0, 0, 0);
        }
    }

    // ---- epilogue: AO[b][s][1024] at head offset, fp32
    const int bb = bh >> 4;
    const int h  = bh & 15;
    float inv[4];
    #pragma unroll
    for (int r = 0; r < 4; ++r) inv[r] = 1.f / lsum[r];
    #pragma unroll
    for (int r = 0; r < 4; ++r) {
        const size_t rowoff = ((size_t)bb*SEQ + qrow0 + lg*4 + r)*D_MODEL + h*HD;
        #pragma unroll
        for (int f = 0; f < 4; ++f)
            AO[rowoff + f*16 + ln] = o[f][r] * inv[r];
    }
}

// ---------------------------------------------------------------------------
// K3: out = AO @ w_out  (M=4096, K=1024, N=1024), fp32
// ---------------------------------------------------------------------------
__global__ __launch_bounds__(256) void gemm_out_kernel(
    const float* __restrict__ A, const float* __restrict__ W,
    float* __restrict__ C)
{
    const int KDIM = D_MODEL;   // 1024
    const int N    = D_MODEL;   // 1024
    __shared__ float As[8][128];
    __shared__ float Bs[8][128];
    const int tid  = threadIdx.x;
    const int tx   = tid & 15;
    const int ty   = tid >> 4;
    const int row0 = blockIdx.y * 128;
    const int col0 = blockIdx.x * 128;
    const int a_row = tid >> 1;
    const int a_col = (tid & 1) << 2;
    const int b_row = tid >> 5;
    const int b_col = (tid & 31) << 2;
    float acc[8][8] = {};
    for (int k0 = 0; k0 < KDIM; k0 += 8) {
        float4 av = *(const float4*)&A[(size_t)(row0 + a_row)*KDIM + k0 + a_col];
        float4 bv = *(const float4*)&W[(size_t)(k0 + b_row)*N + col0 + b_col];
        As[a_col+0][a_row] = av.x;
        As[a_col+1][a_row] = av.y;
        As[a_col+2][a_row] = av.z;
        As[a_col+3][a_row] = av.w;
        *(float4*)&Bs[b_row][b_col] = bv;
        __syncthreads();
        #pragma unroll
        for (int k = 0; k < 8; ++k) {
            float a[8], b[8];
            *(float4*)&a[0] = *(const float4*)&As[k][ty*8];
            *(float4*)&a[4] = *(const float4*)&As[k][ty*8+4];
            *(float4*)&b[0] = *(const float4*)&Bs[k][tx*8];
            *(float4*)&b[4] = *(const float4*)&Bs[k][tx*8+4];
            #pragma unroll
            for (int i = 0; i < 8; ++i)
                #pragma unroll
                for (int j = 0; j < 8; ++j)
                    acc[i][j] = fmaf(a[i], b[j], acc[i][j]);
        }
        __syncthreads();
    }
    #pragma unroll
    for (int i = 0; i < 8; ++i) {
        const int r = row0 + ty*8 + i;
        float* dst = C + (size_t)r*N + col0 + tx*8;
        *(float4*)&dst[0] = make_float4(acc[i][0], acc[i][1], acc[i][2], acc[i][3]);
        *(float4*)&dst[4] = make_float4(acc[i][4], acc[i][5], acc[i][6], acc[i][7]);
    }
}

// ---------------------------------------------------------------------------
extern "C" void kernel_launch(void* const* d_in, const int* in_sizes, int n_in,
                              void* d_out, int out_size, void* d_ws, size_t ws_size,
                              hipStream_t stream)
{
    const float* x     = (const float*)d_in[0];   // (2,2048,1024)
    const float* w_qkv = (const float*)d_in[1];   // (1024,3072)
    const float* w_out = (const float*)d_in[2];   // (1024,1024)
    float* out = (float*)d_out;                   // (2,2048,1024)

    const size_t per = (size_t)BH * SEQ * HD;     // 4,194,304 elements
    unsigned short* Qb = (unsigned short*)d_ws;   // bf16
    unsigned short* Kb = Qb + per;
    unsigned short* Vb = Kb + per;
    float* AO = (float*)(Vb + per);               // fp32 (B,S,D)

    // qkv projection: grid = (N/128, M/128) = (24, 32)
    gemm_qkv_kernel<<<dim3(24, 32), 256, 0, stream>>>(x, w_qkv, Qb, Kb, Vb);
    // causal attention: grid = (S/64, B*H) = (32, 32)
    attn_kernel<<<dim3(SEQ/64, BH), 256, 0, stream>>>(Qb, Kb, Vb, AO);
    // output projection: grid = (N/128, M/128) = (8, 32)
    gemm_out_kernel<<<dim3(8, 32), 256, 0, stream>>>(AO, w_out, out);
}

// Round 10
// 262.270 us; speedup vs baseline: 6.0942x; 2.4383x over previous
//
#include <hip/hip_runtime.h>
#include <hip/hip_bf16.h>
#include <cstddef>

#define D_MODEL 1024
#define NHEAD   16
#define HD      64
#define BATCH   2
#define SEQ     2048
#define BH      (BATCH*NHEAD)   // 32

typedef short bf16x8 __attribute__((ext_vector_type(8)));
typedef unsigned short u16x8 __attribute__((ext_vector_type(8)));
typedef float f32x4  __attribute__((ext_vector_type(4)));

static __device__ __forceinline__ unsigned short f2bf(float f) {
    __hip_bfloat16 h = __float2bfloat16(f);   // RNE
    return __builtin_bit_cast(unsigned short, h);
}
static __device__ __forceinline__ unsigned int pk2(float a, float b) {
    return (unsigned int)f2bf(a) | ((unsigned int)f2bf(b) << 16);
}

// ---------------------------------------------------------------------------
// K0: fp32 -> bf16 conversion, 8 elems/thread, grid-stride.
// ---------------------------------------------------------------------------
__global__ __launch_bounds__(256) void cvt_bf16_kernel(
    const float* __restrict__ src, unsigned short* __restrict__ dst, int n)
{
    const int stride = gridDim.x * blockDim.x;
    for (int i = blockIdx.x*blockDim.x + threadIdx.x; i*8 < n; i += stride) {
        const float4 a = ((const float4*)src)[i*2];
        const float4 b = ((const float4*)src)[i*2+1];
        uint4 w;
        w.x = pk2(a.x, a.y); w.y = pk2(a.z, a.w);
        w.z = pk2(b.x, b.y); w.w = pk2(b.z, b.w);
        ((uint4*)dst)[i] = w;
    }
}

// ---------------------------------------------------------------------------
// K1/K3: bf16 MFMA GEMM, C = A(M x 1024) * B(1024 x NN).
// 128x128 tile, BK=32, 4 waves (2x2 of 64x64), 16x16x32 MFMA.
// A row-major bf16; B row-major bf16, transpose-packed into LDS (Bs[n][k]).
// LDS row stride 44 shorts (88B): all write/read patterns <=2-way bank
// aliasing (free, m136). Layouts (guide-verified m89):
//   A-frag lane = m + 16*(k>>3), 8 consecutive k; B-frag lane = n + 16*(k>>3);
//   C/D: col = lane&15, row = (lane>>4)*4 + reg.
// QKV=true: epilogue scatters bf16 into Q/K/V (BH,S,64).
// QKV=false: epilogue writes fp32 C.
// ---------------------------------------------------------------------------
template<int NN, bool QKV>
__global__ __launch_bounds__(256, 2) void gemm_bf16_kernel(
    const unsigned short* __restrict__ A, const unsigned short* __restrict__ B,
    unsigned short* __restrict__ Qo, unsigned short* __restrict__ Ko,
    unsigned short* __restrict__ Vo, float* __restrict__ Cf)
{
    __shared__ __align__(16) unsigned short As[128][44];
    __shared__ __align__(16) unsigned short Bs[128][44];

    const int tid  = threadIdx.x;
    const int wv   = tid >> 6;
    const int l    = tid & 63;
    const int ln   = l & 15;
    const int lg   = l >> 4;
    const int wrow = (wv >> 1) * 64;
    const int wcol = (wv & 1) * 64;
    const int mtile = blockIdx.y * 128;
    const int ntile = blockIdx.x * 128;

    // staging indices
    const int a_r  = tid >> 2;            // 0..63
    const int a_k  = (tid & 3) * 8;       // 0,8,16,24
    const int b_kp = tid >> 4;            // 0..15 (k-pair)
    const int b_ng = tid & 15;            // 0..15 (8-n group)

    f32x4 acc[4][4] = {};

    for (int kb = 0; kb < 32; ++kb) {
        // ---- stage A (rows a_r and a_r+64)
        const unsigned short* Ag = A + (size_t)(mtile + a_r)*1024 + kb*32 + a_k;
        *(uint4*)&As[a_r     ][a_k] = *(const uint4*)Ag;
        *(uint4*)&As[a_r + 64][a_k] = *(const uint4*)(Ag + (size_t)64*1024);
        // ---- stage B transposed: Bs[n][k], pack k/k+1 pairs
        {
            const int kk = kb*32 + b_kp*2;
            const int nn = ntile + b_ng*8;
            uint4 r0 = *(const uint4*)&B[(size_t)kk*NN + nn];
            uint4 r1 = *(const uint4*)&B[(size_t)(kk+1)*NN + nn];
            u16x8 x0 = __builtin_bit_cast(u16x8, r0);
            u16x8 x1 = __builtin_bit_cast(u16x8, r1);
            #pragma unroll
            for (int j = 0; j < 8; ++j)
                *(unsigned int*)&Bs[b_ng*8 + j][b_kp*2] =
                    (unsigned int)x0[j] | ((unsigned int)x1[j] << 16);
        }
        __syncthreads();
        // ---- compute: 8 ds_read_b128 + 16 MFMA
        bf16x8 af[4], bf[4];
        #pragma unroll
        for (int i = 0; i < 4; ++i)
            af[i] = *(const bf16x8*)&As[wrow + i*16 + ln][lg*8];
        #pragma unroll
        for (int j = 0; j < 4; ++j)
            bf[j] = *(const bf16x8*)&Bs[wcol + j*16 + ln][lg*8];
        #pragma unroll
        for (int i = 0; i < 4; ++i)
            #pragma unroll
            for (int j = 0; j < 4; ++j)
                acc[i][j] = __builtin_amdgcn_mfma_f32_16x16x32_bf16(af[i], bf[j], acc[i][j], 0, 0, 0);
        __syncthreads();
    }

    // ---- epilogue
    #pragma unroll
    for (int i = 0; i < 4; ++i) {
        #pragma unroll
        for (int r = 0; r < 4; ++r) {
            const int mm = mtile + wrow + i*16 + lg*4 + r;
            if constexpr (QKV) {
                const int bb = mm >> 11;
                const int ss = mm & 2047;
                #pragma unroll
                for (int j = 0; j < 4; ++j) {
                    const int cb  = ntile + wcol + j*16 + ln;   // 0..3071
                    const int wch = cb >> 10;
                    const int rem = cb & 1023;
                    const int h   = rem >> 6;
                    const int dd  = rem & 63;
                    unsigned short* dstBase = (wch == 0) ? Qo : (wch == 1) ? Ko : Vo;
                    dstBase[((size_t)(bb*NHEAD + h)*SEQ + ss)*HD + dd] = f2bf(acc[i][j][r]);
                }
            } else {
                #pragma unroll
                for (int j = 0; j < 4; ++j) {
                    const int cb = ntile + wcol + j*16 + ln;
                    Cf[(size_t)mm*NN + cb] = acc[i][j][r];
                }
            }
        }
    }
}

// ---------------------------------------------------------------------------
// K2 v6: causal flash attention, bf16 MFMA (16x16x32). Same as v5 (passing,
// absmax .0156) except epilogue writes AO in bf16 for the bf16 out-GEMM.
// ---------------------------------------------------------------------------
__global__ __launch_bounds__(256, 2) void attn_kernel(
    const unsigned short* __restrict__ Qb, const unsigned short* __restrict__ Kb,
    const unsigned short* __restrict__ Vb, unsigned short* __restrict__ AO)
{
    __shared__ __align__(16) unsigned short Ks[2][32][72];  // keys x dims(+pad)
    __shared__ __align__(16) unsigned short Vt[2][64][40];  // dims x keys(+pad)
    __shared__ __align__(16) unsigned short Pl[4][16][32];  // per-wave P

    const int tid = threadIdx.x;
    const int wv  = tid >> 6;
    const int l   = tid & 63;
    const int ln  = l & 15;
    const int lg  = l >> 4;
    const int bh  = blockIdx.y;
    const int qt  = 31 - blockIdx.x; // long blocks first
    const int qrow0 = qt*64 + wv*16;
    const int nT  = 2*qt + 2;

    const unsigned short* Qbh = Qb + (size_t)bh*SEQ*HD;
    const unsigned short* Kbh = Kb + (size_t)bh*SEQ*HD;
    const unsigned short* Vbh = Vb + (size_t)bh*SEQ*HD;

    const bf16x8 q0 = *(const bf16x8*)&Qbh[(size_t)(qrow0 + ln)*HD + lg*8];
    const bf16x8 q1 = *(const bf16x8*)&Qbh[(size_t)(qrow0 + ln)*HD + 32 + lg*8];

    f32x4 o[4] = {};
    float m[4], lsum[4];
    #pragma unroll
    for (int r = 0; r < 4; ++r) { m[r] = -1e30f; lsum[r] = 0.f; }

    const int s_kl = tid >> 3;
    const int s_d0 = (tid & 7) << 3;
    const int s_dg = tid >> 4;
    const int s_kp = (tid & 15) << 1;

    {
        const int kt = 0;
        *(uint4*)&Ks[0][s_kl][s_d0] = *(const uint4*)&Kbh[(size_t)(kt + s_kl)*HD + s_d0];
        uint2 va = *(const uint2*)&Vbh[(size_t)(kt + s_kp    )*HD + s_dg*4];
        uint2 vb = *(const uint2*)&Vbh[(size_t)(kt + s_kp + 1)*HD + s_dg*4];
        *(unsigned int*)&Vt[0][s_dg*4+0][s_kp] = (va.x & 0xffffu) | (vb.x << 16);
        *(unsigned int*)&Vt[0][s_dg*4+1][s_kp] = (va.x >> 16)     | (vb.x & 0xffff0000u);
        *(unsigned int*)&Vt[0][s_dg*4+2][s_kp] = (va.y & 0xffffu) | (vb.y << 16);
        *(unsigned int*)&Vt[0][s_dg*4+3][s_kp] = (va.y >> 16)     | (vb.y & 0xffff0000u);
    }

    for (int t = 0; t < nT; ++t) {
        __syncthreads();
        const int buf = t & 1;
        if (t + 1 < nT) {
            const int kt = (t + 1) * 32;
            const int nb = buf ^ 1;
            *(uint4*)&Ks[nb][s_kl][s_d0] = *(const uint4*)&Kbh[(size_t)(kt + s_kl)*HD + s_d0];
            uint2 va = *(const uint2*)&Vbh[(size_t)(kt + s_kp    )*HD + s_dg*4];
            uint2 vb = *(const uint2*)&Vbh[(size_t)(kt + s_kp + 1)*HD + s_dg*4];
            *(unsigned int*)&Vt[nb][s_dg*4+0][s_kp] = (va.x & 0xffffu) | (vb.x << 16);
            *(unsigned int*)&Vt[nb][s_dg*4+1][s_kp] = (va.x >> 16)     | (vb.x & 0xffff0000u);
            *(unsigned int*)&Vt[nb][s_dg*4+2][s_kp] = (va.y & 0xffffu) | (vb.y << 16);
            *(unsigned int*)&Vt[nb][s_dg*4+3][s_kp] = (va.y >> 16)     | (vb.y & 0xffff0000u);
        }
        const int kt = t * 32;
        if (kt > qrow0 + 15) continue;

        bf16x8 k00 = *(const bf16x8*)&Ks[buf][ln     ][lg*8];
        bf16x8 k01 = *(const bf16x8*)&Ks[buf][ln     ][32 + lg*8];
        bf16x8 k10 = *(const bf16x8*)&Ks[buf][16 + ln][lg*8];
        bf16x8 k11 = *(const bf16x8*)&Ks[buf][16 + ln][32 + lg*8];
        f32x4 s0 = {}, s1 = {};
        s0 = __builtin_amdgcn_mfma_f32_16x16x32_bf16(q0, k00, s0, 0, 0, 0);
        s0 = __builtin_amdgcn_mfma_f32_16x16x32_bf16(q1, k01, s0, 0, 0, 0);
        s1 = __builtin_amdgcn_mfma_f32_16x16x32_bf16(q0, k10, s1, 0, 0, 0);
        s1 = __builtin_amdgcn_mfma_f32_16x16x32_bf16(q1, k11, s1, 0, 0, 0);

        float mt[4];
        #pragma unroll
        for (int r = 0; r < 4; ++r) {
            const int qg = qrow0 + lg*4 + r;
            float a = s0[r] * 0.125f, b = s1[r] * 0.125f;
            a = (kt + ln      > qg) ? -1e30f : a;
            b = (kt + 16 + ln > qg) ? -1e30f : b;
            s0[r] = a; s1[r] = b;
            mt[r] = fmaxf(a, b);
        }
        #pragma unroll
        for (int d = 1; d <= 8; d <<= 1) {
            #pragma unroll
            for (int r = 0; r < 4; ++r) mt[r] = fmaxf(mt[r], __shfl_xor(mt[r], d));
        }
        float alpha[4], ps[4];
        #pragma unroll
        for (int r = 0; r < 4; ++r) {
            const float mnew = fmaxf(m[r], mt[r]);
            alpha[r] = __expf(m[r] - mnew);
            m[r] = mnew;
            s0[r] = __expf(s0[r] - mnew);
            s1[r] = __expf(s1[r] - mnew);
            ps[r] = s0[r] + s1[r];
        }
        #pragma unroll
        for (int d = 1; d <= 8; d <<= 1) {
            #pragma unroll
            for (int r = 0; r < 4; ++r) ps[r] += __shfl_xor(ps[r], d);
        }
        #pragma unroll
        for (int r = 0; r < 4; ++r) {
            lsum[r] = lsum[r]*alpha[r] + ps[r];
            #pragma unroll
            for (int f = 0; f < 4; ++f) o[f][r] *= alpha[r];
        }

        #pragma unroll
        for (int r = 0; r < 4; ++r) {
            Pl[wv][lg*4 + r][ln]      = f2bf(s0[r]);
            Pl[wv][lg*4 + r][16 + ln] = f2bf(s1[r]);
        }
        bf16x8 pa = *(const bf16x8*)&Pl[wv][ln][lg*8];

        #pragma unroll
        for (int f = 0; f < 4; ++f) {
            bf16x8 vf = *(const bf16x8*)&Vt[buf][f*16 + ln][lg*8];
            o[f] = __builtin_amdgcn_mfma_f32_16x16x32_bf16(pa, vf, o[f], 0, 0, 0);
        }
    }

    // ---- epilogue: AO bf16 [B][S][1024] at head offset
    const int bb = bh >> 4;
    const int h  = bh & 15;
    float inv[4];
    #pragma unroll
    for (int r = 0; r < 4; ++r) inv[r] = 1.f / lsum[r];
    #pragma unroll
    for (int r = 0; r < 4; ++r) {
        const size_t rowoff = ((size_t)bb*SEQ + qrow0 + lg*4 + r)*D_MODEL + h*HD;
        #pragma unroll
        for (int f = 0; f < 4; ++f)
            AO[rowoff + f*16 + ln] = f2bf(o[f][r] * inv[r]);
    }
}

// ---------------------------------------------------------------------------
extern "C" void kernel_launch(void* const* d_in, const int* in_sizes, int n_in,
                              void* d_out, int out_size, void* d_ws, size_t ws_size,
                              hipStream_t stream)
{
    const float* x     = (const float*)d_in[0];   // (2,2048,1024)
    const float* w_qkv = (const float*)d_in[1];   // (1024,3072)
    const float* w_out = (const float*)d_in[2];   // (1024,1024)
    float* out = (float*)d_out;                   // (2,2048,1024)

    const size_t nX  = (size_t)BATCH*SEQ*D_MODEL;      // 4 Mi
    const size_t nWq = (size_t)D_MODEL*3*D_MODEL;      // 3 Mi
    const size_t nWo = (size_t)D_MODEL*D_MODEL;        // 1 Mi
    const size_t per = (size_t)BH * SEQ * HD;          // 4 Mi

    unsigned short* Xb  = (unsigned short*)d_ws;       // bf16 x
    unsigned short* Wqb = Xb  + nX;
    unsigned short* Wob = Wqb + nWq;
    unsigned short* Qb  = Wob + nWo;
    unsigned short* Kb  = Qb + per;
    unsigned short* Vb  = Kb + per;
    unsigned short* AOb = Vb + per;                    // bf16 (B,S,D)

    cvt_bf16_kernel<<<1024, 256, 0, stream>>>(x,     Xb,  (int)nX);
    cvt_bf16_kernel<<<1024, 256, 0, stream>>>(w_qkv, Wqb, (int)nWq);
    cvt_bf16_kernel<<<512,  256, 0, stream>>>(w_out, Wob, (int)nWo);

    // qkv projection: grid = (N/128, M/128) = (24, 32)
    gemm_bf16_kernel<3*D_MODEL, true><<<dim3(24, 32), 256, 0, stream>>>(
        Xb, Wqb, Qb, Kb, Vb, nullptr);
    // causal attention: grid = (S/64, B*H) = (32, 32)
    attn_kernel<<<dim3(SEQ/64, BH), 256, 0, stream>>>(Qb, Kb, Vb, AOb);
    // output projection: grid = (N/128, M/128) = (8, 32)
    gemm_bf16_kernel<D_MODEL, false><<<dim3(8, 32), 256, 0, stream>>>(
        AOb, Wob, nullptr, nullptr, nullptr, out);
}

// Round 11
// 258.029 us; speedup vs baseline: 6.1943x; 1.0164x over previous
//
#include <hip/hip_runtime.h>
#include <hip/hip_bf16.h>
#include <cstddef>

#define D_MODEL 1024
#define NHEAD   16
#define HD      64
#define BATCH   2
#define SEQ     2048
#define BH      (BATCH*NHEAD)   // 32

typedef short bf16x8 __attribute__((ext_vector_type(8)));
typedef unsigned short u16x8 __attribute__((ext_vector_type(8)));
typedef float f32x4  __attribute__((ext_vector_type(4)));

static __device__ __forceinline__ unsigned short f2bf(float f) {
    __hip_bfloat16 h = __float2bfloat16(f);   // RNE
    return __builtin_bit_cast(unsigned short, h);
}
static __device__ __forceinline__ unsigned int pk2(float a, float b) {
    return (unsigned int)f2bf(a) | ((unsigned int)f2bf(b) << 16);
}

// ---------------------------------------------------------------------------
// K0: fp32 -> bf16 for x, w_qkv, w_out in ONE launch. dst ranges are
// contiguous in ws (Xb | Wqb | Wob). 8 elems/thread, grid-stride.
// ---------------------------------------------------------------------------
__global__ __launch_bounds__(256) void cvt3_kernel(
    const float* __restrict__ a, int na8,      // x,      groups of 8
    const float* __restrict__ b, int nb8,      // w_qkv
    const float* __restrict__ c, int nc8,      // w_out
    unsigned short* __restrict__ dst)
{
    const int tot = na8 + nb8 + nc8;
    const int stride = gridDim.x * blockDim.x;
    for (int i = blockIdx.x*blockDim.x + threadIdx.x; i < tot; i += stride) {
        const float* s; int off;
        if (i < na8)            { s = a; off = i; }
        else if (i < na8 + nb8) { s = b; off = i - na8; }
        else                    { s = c; off = i - na8 - nb8; }
        const float4 p = ((const float4*)s)[off*2];
        const float4 q = ((const float4*)s)[off*2+1];
        uint4 w;
        w.x = pk2(p.x, p.y); w.y = pk2(p.z, p.w);
        w.z = pk2(q.x, q.y); w.w = pk2(q.z, q.w);
        ((uint4*)dst)[i] = w;
    }
}

// ---------------------------------------------------------------------------
// K1/K3: bf16 MFMA GEMM, C = A(M x 1024) * B(1024 x NN).
// 128x128 tile, BK=32, 4 waves (2x2 of 64x64), 16x16x32 MFMA.
// A row-major bf16; B row-major bf16, transpose-packed into LDS (Bs[n][k]).
// LDS row stride 44 shorts (88B). Layouts (guide-verified m89):
//   A-frag lane = m + 16*(k>>3), 8 consecutive k; B-frag lane = n + 16*(k>>3);
//   C/D: col = lane&15, row = (lane>>4)*4 + reg.
// QKV=true: epilogue scatters bf16 into Q/K/V (BH,S,64).
// QKV=false: epilogue writes fp32 C.
// ---------------------------------------------------------------------------
template<int NN, bool QKV>
__global__ __launch_bounds__(256, 2) void gemm_bf16_kernel(
    const unsigned short* __restrict__ A, const unsigned short* __restrict__ B,
    unsigned short* __restrict__ Qo, unsigned short* __restrict__ Ko,
    unsigned short* __restrict__ Vo, float* __restrict__ Cf)
{
    __shared__ __align__(16) unsigned short As[128][44];
    __shared__ __align__(16) unsigned short Bs[128][44];

    const int tid  = threadIdx.x;
    const int wv   = tid >> 6;
    const int l    = tid & 63;
    const int ln   = l & 15;
    const int lg   = l >> 4;
    const int wrow = (wv >> 1) * 64;
    const int wcol = (wv & 1) * 64;
    const int mtile = blockIdx.y * 128;
    const int ntile = blockIdx.x * 128;

    // staging indices
    const int a_r  = tid >> 2;            // 0..63
    const int a_k  = (tid & 3) * 8;       // 0,8,16,24
    const int b_kp = tid >> 4;            // 0..15 (k-pair)
    const int b_ng = tid & 15;            // 0..15 (8-n group)

    f32x4 acc[4][4] = {};

    for (int kb = 0; kb < 32; ++kb) {
        // ---- stage A (rows a_r and a_r+64)
        const unsigned short* Ag = A + (size_t)(mtile + a_r)*1024 + kb*32 + a_k;
        *(uint4*)&As[a_r     ][a_k] = *(const uint4*)Ag;
        *(uint4*)&As[a_r + 64][a_k] = *(const uint4*)(Ag + (size_t)64*1024);
        // ---- stage B transposed: Bs[n][k], pack k/k+1 pairs
        {
            const int kk = kb*32 + b_kp*2;
            const int nn = ntile + b_ng*8;
            uint4 r0 = *(const uint4*)&B[(size_t)kk*NN + nn];
            uint4 r1 = *(const uint4*)&B[(size_t)(kk+1)*NN + nn];
            u16x8 x0 = __builtin_bit_cast(u16x8, r0);
            u16x8 x1 = __builtin_bit_cast(u16x8, r1);
            #pragma unroll
            for (int j = 0; j < 8; ++j)
                *(unsigned int*)&Bs[b_ng*8 + j][b_kp*2] =
                    (unsigned int)x0[j] | ((unsigned int)x1[j] << 16);
        }
        __syncthreads();
        // ---- compute: 8 ds_read_b128 + 16 MFMA
        bf16x8 af[4], bf[4];
        #pragma unroll
        for (int i = 0; i < 4; ++i)
            af[i] = *(const bf16x8*)&As[wrow + i*16 + ln][lg*8];
        #pragma unroll
        for (int j = 0; j < 4; ++j)
            bf[j] = *(const bf16x8*)&Bs[wcol + j*16 + ln][lg*8];
        #pragma unroll
        for (int i = 0; i < 4; ++i)
            #pragma unroll
            for (int j = 0; j < 4; ++j)
                acc[i][j] = __builtin_amdgcn_mfma_f32_16x16x32_bf16(af[i], bf[j], acc[i][j], 0, 0, 0);
        __syncthreads();
    }

    // ---- epilogue
    #pragma unroll
    for (int i = 0; i < 4; ++i) {
        #pragma unroll
        for (int r = 0; r < 4; ++r) {
            const int mm = mtile + wrow + i*16 + lg*4 + r;
            if constexpr (QKV) {
                const int bb = mm >> 11;
                const int ss = mm & 2047;
                #pragma unroll
                for (int j = 0; j < 4; ++j) {
                    const int cb  = ntile + wcol + j*16 + ln;   // 0..3071
                    const int wch = cb >> 10;
                    const int rem = cb & 1023;
                    const int h   = rem >> 6;
                    const int dd  = rem & 63;
                    unsigned short* dstBase = (wch == 0) ? Qo : (wch == 1) ? Ko : Vo;
                    dstBase[((size_t)(bb*NHEAD + h)*SEQ + ss)*HD + dd] = f2bf(acc[i][j][r]);
                }
            } else {
                #pragma unroll
                for (int j = 0; j < 4; ++j) {
                    const int cb = ntile + wcol + j*16 + ln;
                    Cf[(size_t)mm*NN + cb] = acc[i][j][r];
                }
            }
        }
    }
}

// ---------------------------------------------------------------------------
// K2 v7: causal flash attention, bf16 MFMA (16x16x32). Identical to v6
// (passing, absmax .0156) except __launch_bounds__(256,4): kernel uses only
// 44 VGPR, so 4 blocks/CU fit (LDS 4x23.5=94KB<160KB; VGPR cap 128>44).
// v6's (256,2) self-capped occupancy at 25%; grid=1024 blocks = 4/CU -> 50%.
// ---------------------------------------------------------------------------
__global__ __launch_bounds__(256, 4) void attn_kernel(
    const unsigned short* __restrict__ Qb, const unsigned short* __restrict__ Kb,
    const unsigned short* __restrict__ Vb, unsigned short* __restrict__ AO)
{
    __shared__ __align__(16) unsigned short Ks[2][32][72];  // keys x dims(+pad)
    __shared__ __align__(16) unsigned short Vt[2][64][40];  // dims x keys(+pad)
    __shared__ __align__(16) unsigned short Pl[4][16][32];  // per-wave P

    const int tid = threadIdx.x;
    const int wv  = tid >> 6;
    const int l   = tid & 63;
    const int ln  = l & 15;
    const int lg  = l >> 4;
    const int bh  = blockIdx.y;
    const int qt  = 31 - blockIdx.x; // long blocks first
    const int qrow0 = qt*64 + wv*16;
    const int nT  = 2*qt + 2;

    const unsigned short* Qbh = Qb + (size_t)bh*SEQ*HD;
    const unsigned short* Kbh = Kb + (size_t)bh*SEQ*HD;
    const unsigned short* Vbh = Vb + (size_t)bh*SEQ*HD;

    const bf16x8 q0 = *(const bf16x8*)&Qbh[(size_t)(qrow0 + ln)*HD + lg*8];
    const bf16x8 q1 = *(const bf16x8*)&Qbh[(size_t)(qrow0 + ln)*HD + 32 + lg*8];

    f32x4 o[4] = {};
    float m[4], lsum[4];
    #pragma unroll
    for (int r = 0; r < 4; ++r) { m[r] = -1e30f; lsum[r] = 0.f; }

    const int s_kl = tid >> 3;
    const int s_d0 = (tid & 7) << 3;
    const int s_dg = tid >> 4;
    const int s_kp = (tid & 15) << 1;

    {
        const int kt = 0;
        *(uint4*)&Ks[0][s_kl][s_d0] = *(const uint4*)&Kbh[(size_t)(kt + s_kl)*HD + s_d0];
        uint2 va = *(const uint2*)&Vbh[(size_t)(kt + s_kp    )*HD + s_dg*4];
        uint2 vb = *(const uint2*)&Vbh[(size_t)(kt + s_kp + 1)*HD + s_dg*4];
        *(unsigned int*)&Vt[0][s_dg*4+0][s_kp] = (va.x & 0xffffu) | (vb.x << 16);
        *(unsigned int*)&Vt[0][s_dg*4+1][s_kp] = (va.x >> 16)     | (vb.x & 0xffff0000u);
        *(unsigned int*)&Vt[0][s_dg*4+2][s_kp] = (va.y & 0xffffu) | (vb.y << 16);
        *(unsigned int*)&Vt[0][s_dg*4+3][s_kp] = (va.y >> 16)     | (vb.y & 0xffff0000u);
    }

    for (int t = 0; t < nT; ++t) {
        __syncthreads();
        const int buf = t & 1;
        if (t + 1 < nT) {
            const int kt = (t + 1) * 32;
            const int nb = buf ^ 1;
            *(uint4*)&Ks[nb][s_kl][s_d0] = *(const uint4*)&Kbh[(size_t)(kt + s_kl)*HD + s_d0];
            uint2 va = *(const uint2*)&Vbh[(size_t)(kt + s_kp    )*HD + s_dg*4];
            uint2 vb = *(const uint2*)&Vbh[(size_t)(kt + s_kp + 1)*HD + s_dg*4];
            *(unsigned int*)&Vt[nb][s_dg*4+0][s_kp] = (va.x & 0xffffu) | (vb.x << 16);
            *(unsigned int*)&Vt[nb][s_dg*4+1][s_kp] = (va.x >> 16)     | (vb.x & 0xffff0000u);
            *(unsigned int*)&Vt[nb][s_dg*4+2][s_kp] = (va.y & 0xffffu) | (vb.y << 16);
            *(unsigned int*)&Vt[nb][s_dg*4+3][s_kp] = (va.y >> 16)     | (vb.y & 0xffff0000u);
        }
        const int kt = t * 32;
        if (kt > qrow0 + 15) continue;

        bf16x8 k00 = *(const bf16x8*)&Ks[buf][ln     ][lg*8];
        bf16x8 k01 = *(const bf16x8*)&Ks[buf][ln     ][32 + lg*8];
        bf16x8 k10 = *(const bf16x8*)&Ks[buf][16 + ln][lg*8];
        bf16x8 k11 = *(const bf16x8*)&Ks[buf][16 + ln][32 + lg*8];
        f32x4 s0 = {}, s1 = {};
        s0 = __builtin_amdgcn_mfma_f32_16x16x32_bf16(q0, k00, s0, 0, 0, 0);
        s0 = __builtin_amdgcn_mfma_f32_16x16x32_bf16(q1, k01, s0, 0, 0, 0);
        s1 = __builtin_amdgcn_mfma_f32_16x16x32_bf16(q0, k10, s1, 0, 0, 0);
        s1 = __builtin_amdgcn_mfma_f32_16x16x32_bf16(q1, k11, s1, 0, 0, 0);

        float mt[4];
        #pragma unroll
        for (int r = 0; r < 4; ++r) {
            const int qg = qrow0 + lg*4 + r;
            float a = s0[r] * 0.125f, b = s1[r] * 0.125f;
            a = (kt + ln      > qg) ? -1e30f : a;
            b = (kt + 16 + ln > qg) ? -1e30f : b;
            s0[r] = a; s1[r] = b;
            mt[r] = fmaxf(a, b);
        }
        #pragma unroll
        for (int d = 1; d <= 8; d <<= 1) {
            #pragma unroll
            for (int r = 0; r < 4; ++r) mt[r] = fmaxf(mt[r], __shfl_xor(mt[r], d));
        }
        float alpha[4], ps[4];
        #pragma unroll
        for (int r = 0; r < 4; ++r) {
            const float mnew = fmaxf(m[r], mt[r]);
            alpha[r] = __expf(m[r] - mnew);
            m[r] = mnew;
            s0[r] = __expf(s0[r] - mnew);
            s1[r] = __expf(s1[r] - mnew);
            ps[r] = s0[r] + s1[r];
        }
        #pragma unroll
        for (int d = 1; d <= 8; d <<= 1) {
            #pragma unroll
            for (int r = 0; r < 4; ++r) ps[r] += __shfl_xor(ps[r], d);
        }
        #pragma unroll
        for (int r = 0; r < 4; ++r) {
            lsum[r] = lsum[r]*alpha[r] + ps[r];
            #pragma unroll
            for (int f = 0; f < 4; ++f) o[f][r] *= alpha[r];
        }

        #pragma unroll
        for (int r = 0; r < 4; ++r) {
            Pl[wv][lg*4 + r][ln]      = f2bf(s0[r]);
            Pl[wv][lg*4 + r][16 + ln] = f2bf(s1[r]);
        }
        bf16x8 pa = *(const bf16x8*)&Pl[wv][ln][lg*8];

        #pragma unroll
        for (int f = 0; f < 4; ++f) {
            bf16x8 vf = *(const bf16x8*)&Vt[buf][f*16 + ln][lg*8];
            o[f] = __builtin_amdgcn_mfma_f32_16x16x32_bf16(pa, vf, o[f], 0, 0, 0);
        }
    }

    // ---- epilogue: AO bf16 [B][S][1024] at head offset
    const int bb = bh >> 4;
    const int h  = bh & 15;
    float inv[4];
    #pragma unroll
    for (int r = 0; r < 4; ++r) inv[r] = 1.f / lsum[r];
    #pragma unroll
    for (int r = 0; r < 4; ++r) {
        const size_t rowoff = ((size_t)bb*SEQ + qrow0 + lg*4 + r)*D_MODEL + h*HD;
        #pragma unroll
        for (int f = 0; f < 4; ++f)
            AO[rowoff + f*16 + ln] = f2bf(o[f][r] * inv[r]);
    }
}

// ---------------------------------------------------------------------------
extern "C" void kernel_launch(void* const* d_in, const int* in_sizes, int n_in,
                              void* d_out, int out_size, void* d_ws, size_t ws_size,
                              hipStream_t stream)
{
    const float* x     = (const float*)d_in[0];   // (2,2048,1024)
    const float* w_qkv = (const float*)d_in[1];   // (1024,3072)
    const float* w_out = (const float*)d_in[2];   // (1024,1024)
    float* out = (float*)d_out;                   // (2,2048,1024)

    const size_t nX  = (size_t)BATCH*SEQ*D_MODEL;      // 4 Mi
    const size_t nWq = (size_t)D_MODEL*3*D_MODEL;      // 3 Mi
    const size_t nWo = (size_t)D_MODEL*D_MODEL;        // 1 Mi
    const size_t per = (size_t)BH * SEQ * HD;          // 4 Mi

    unsigned short* Xb  = (unsigned short*)d_ws;       // bf16 x | w_qkv | w_out contiguous
    unsigned short* Wqb = Xb  + nX;
    unsigned short* Wob = Wqb + nWq;
    unsigned short* Qb  = Wob + nWo;
    unsigned short* Kb  = Qb + per;
    unsigned short* Vb  = Kb + per;
    unsigned short* AOb = Vb + per;                    // bf16 (B,S,D)

    cvt3_kernel<<<1024, 256, 0, stream>>>(
        x, (int)(nX/8), w_qkv, (int)(nWq/8), w_out, (int)(nWo/8), Xb);

    // qkv projection: grid = (N/128, M/128) = (24, 32)
    gemm_bf16_kernel<3*D_MODEL, true><<<dim3(24, 32), 256, 0, stream>>>(
        Xb, Wqb, Qb, Kb, Vb, nullptr);
    // causal attention: grid = (S/64, B*H) = (32, 32)
    attn_kernel<<<dim3(SEQ/64, BH), 256, 0, stream>>>(Qb, Kb, Vb, AOb);
    // output projection: grid = (N/128, M/128) = (8, 32)
    gemm_bf16_kernel<D_MODEL, false><<<dim3(8, 32), 256, 0, stream>>>(
        AOb, Wob, nullptr, nullptr, nullptr, out);
}

// Round 12
// 174.288 us; speedup vs baseline: 9.1705x; 1.4805x over previous
//
#include <hip/hip_runtime.h>
#include <hip/hip_bf16.h>
#include <cstddef>

#define D_MODEL 1024
#define NHEAD   16
#define HD      64
#define BATCH   2
#define SEQ     2048
#define BH      (BATCH*NHEAD)   // 32

typedef short bf16x8 __attribute__((ext_vector_type(8)));
typedef unsigned short u16x8 __attribute__((ext_vector_type(8)));
typedef float f32x4  __attribute__((ext_vector_type(4)));

static __device__ __forceinline__ unsigned short f2bf(float f) {
    __hip_bfloat16 h = __float2bfloat16(f);   // RNE
    return __builtin_bit_cast(unsigned short, h);
}
static __device__ __forceinline__ unsigned int pk2(float a, float b) {
    return (unsigned int)f2bf(a) | ((unsigned int)f2bf(b) << 16);
}

// ---------------------------------------------------------------------------
// K0: fp32 -> bf16 for x, w_qkv, w_out in ONE launch (dst contiguous in ws).
// ---------------------------------------------------------------------------
__global__ __launch_bounds__(256) void cvt3_kernel(
    const float* __restrict__ a, int na8,
    const float* __restrict__ b, int nb8,
    const float* __restrict__ c, int nc8,
    unsigned short* __restrict__ dst)
{
    const int tot = na8 + nb8 + nc8;
    const int stride = gridDim.x * blockDim.x;
    for (int i = blockIdx.x*blockDim.x + threadIdx.x; i < tot; i += stride) {
        const float* s; int off;
        if (i < na8)            { s = a; off = i; }
        else if (i < na8 + nb8) { s = b; off = i - na8; }
        else                    { s = c; off = i - na8 - nb8; }
        const float4 p = ((const float4*)s)[off*2];
        const float4 q = ((const float4*)s)[off*2+1];
        uint4 w;
        w.x = pk2(p.x, p.y); w.y = pk2(p.z, p.w);
        w.z = pk2(q.x, q.y); w.w = pk2(q.z, q.w);
        ((uint4*)dst)[i] = w;
    }
}

// ---------------------------------------------------------------------------
// K1/K3: bf16 MFMA GEMM, C = A(M x 1024) * B(1024 x NN). Unchanged (R10).
// ---------------------------------------------------------------------------
template<int NN, bool QKV>
__global__ __launch_bounds__(256, 2) void gemm_bf16_kernel(
    const unsigned short* __restrict__ A, const unsigned short* __restrict__ B,
    unsigned short* __restrict__ Qo, unsigned short* __restrict__ Ko,
    unsigned short* __restrict__ Vo, float* __restrict__ Cf)
{
    __shared__ __align__(16) unsigned short As[128][44];
    __shared__ __align__(16) unsigned short Bs[128][44];

    const int tid  = threadIdx.x;
    const int wv   = tid >> 6;
    const int l    = tid & 63;
    const int ln   = l & 15;
    const int lg   = l >> 4;
    const int wrow = (wv >> 1) * 64;
    const int wcol = (wv & 1) * 64;
    const int mtile = blockIdx.y * 128;
    const int ntile = blockIdx.x * 128;

    const int a_r  = tid >> 2;
    const int a_k  = (tid & 3) * 8;
    const int b_kp = tid >> 4;
    const int b_ng = tid & 15;

    f32x4 acc[4][4] = {};

    for (int kb = 0; kb < 32; ++kb) {
        const unsigned short* Ag = A + (size_t)(mtile + a_r)*1024 + kb*32 + a_k;
        *(uint4*)&As[a_r     ][a_k] = *(const uint4*)Ag;
        *(uint4*)&As[a_r + 64][a_k] = *(const uint4*)(Ag + (size_t)64*1024);
        {
            const int kk = kb*32 + b_kp*2;
            const int nn = ntile + b_ng*8;
            uint4 r0 = *(const uint4*)&B[(size_t)kk*NN + nn];
            uint4 r1 = *(const uint4*)&B[(size_t)(kk+1)*NN + nn];
            u16x8 x0 = __builtin_bit_cast(u16x8, r0);
            u16x8 x1 = __builtin_bit_cast(u16x8, r1);
            #pragma unroll
            for (int j = 0; j < 8; ++j)
                *(unsigned int*)&Bs[b_ng*8 + j][b_kp*2] =
                    (unsigned int)x0[j] | ((unsigned int)x1[j] << 16);
        }
        __syncthreads();
        bf16x8 af[4], bf[4];
        #pragma unroll
        for (int i = 0; i < 4; ++i)
            af[i] = *(const bf16x8*)&As[wrow + i*16 + ln][lg*8];
        #pragma unroll
        for (int j = 0; j < 4; ++j)
            bf[j] = *(const bf16x8*)&Bs[wcol + j*16 + ln][lg*8];
        #pragma unroll
        for (int i = 0; i < 4; ++i)
            #pragma unroll
            for (int j = 0; j < 4; ++j)
                acc[i][j] = __builtin_amdgcn_mfma_f32_16x16x32_bf16(af[i], bf[j], acc[i][j], 0, 0, 0);
        __syncthreads();
    }

    #pragma unroll
    for (int i = 0; i < 4; ++i) {
        #pragma unroll
        for (int r = 0; r < 4; ++r) {
            const int mm = mtile + wrow + i*16 + lg*4 + r;
            if constexpr (QKV) {
                const int bb = mm >> 11;
                const int ss = mm & 2047;
                #pragma unroll
                for (int j = 0; j < 4; ++j) {
                    const int cb  = ntile + wcol + j*16 + ln;
                    const int wch = cb >> 10;
                    const int rem = cb & 1023;
                    const int h   = rem >> 6;
                    const int dd  = rem & 63;
                    unsigned short* dstBase = (wch == 0) ? Qo : (wch == 1) ? Ko : Vo;
                    dstBase[((size_t)(bb*NHEAD + h)*SEQ + ss)*HD + dd] = f2bf(acc[i][j][r]);
                }
            } else {
                #pragma unroll
                for (int j = 0; j < 4; ++j) {
                    const int cb = ntile + wcol + j*16 + ln;
                    Cf[(size_t)mm*NN + cb] = acc[i][j][r];
                }
            }
        }
    }
}

// ---------------------------------------------------------------------------
// K2 v8: causal flash attention, bf16 MFMA, KVBLK=64, paired q-tiles.
// Block bx handles q-tiles qtA=31-bx and qtB=bx sequentially: key-tile count
// = (qtA+1)+(qtB+1) = 33 for EVERY block -> perfectly balanced; grid (16,32)
// = 512 blocks = 2/CU. Per 64-key tile: 8 QK MFMA + 8 PV MFMA, ONE pair of
// softmax trees (in-lane reduce over 4 score vecs first). Halves the serial
// chain count vs v7 (which was critical-path-bound: 64 tiles x ~2.7us).
// Layouts as v5 (verified): A lane=m+16*(k>>3); B lane=n+16*(k>>3);
// C/D col=lane&15,row=(lane>>4)*4+reg. Ks/Vt stride 72 (2-way, free);
// Pl stride 76 (conflict-free P writes).
// ---------------------------------------------------------------------------
__global__ __launch_bounds__(256, 2) void attn_kernel(
    const unsigned short* __restrict__ Qb, const unsigned short* __restrict__ Kb,
    const unsigned short* __restrict__ Vb, unsigned short* __restrict__ AO)
{
    __shared__ __align__(16) unsigned short Ks[2][64][72];  // keys x dims(+pad)
    __shared__ __align__(16) unsigned short Vt[2][64][72];  // dims x keys(+pad)
    __shared__ __align__(16) unsigned short Pl[4][16][76];  // per-wave P 16x64

    const int tid = threadIdx.x;
    const int wv  = tid >> 6;
    const int l   = tid & 63;
    const int ln  = l & 15;
    const int lg  = l >> 4;
    const int bh  = blockIdx.y;
    const int bx  = blockIdx.x;          // 0..15
    const int qtA = 31 - bx;
    const int qtB = bx;
    const int nTA = qtA + 1;
    const int nT  = nTA + qtB + 1;       // 33 always

    const unsigned short* Qbh = Qb + (size_t)bh*SEQ*HD;
    const unsigned short* Kbh = Kb + (size_t)bh*SEQ*HD;
    const unsigned short* Vbh = Vb + (size_t)bh*SEQ*HD;

    // staging indices
    const int s_kl = tid >> 3;            // key 0..31 (and +32)
    const int s_d0 = (tid & 7) << 3;      // dim0
    const int s_dg = tid >> 4;            // dim group 0..15
    const int s_kp = (tid & 15) << 1;     // key pair (and +32)

    auto stage = [&](int nb, int kt) {
        *(uint4*)&Ks[nb][s_kl     ][s_d0] = *(const uint4*)&Kbh[(size_t)(kt + s_kl     )*HD + s_d0];
        *(uint4*)&Ks[nb][s_kl + 32][s_d0] = *(const uint4*)&Kbh[(size_t)(kt + s_kl + 32)*HD + s_d0];
        uint2 va0 = *(const uint2*)&Vbh[(size_t)(kt + s_kp     )*HD + s_dg*4];
        uint2 vb0 = *(const uint2*)&Vbh[(size_t)(kt + s_kp + 1 )*HD + s_dg*4];
        uint2 va1 = *(const uint2*)&Vbh[(size_t)(kt + s_kp + 32)*HD + s_dg*4];
        uint2 vb1 = *(const uint2*)&Vbh[(size_t)(kt + s_kp + 33)*HD + s_dg*4];
        *(unsigned int*)&Vt[nb][s_dg*4+0][s_kp]    = (va0.x & 0xffffu) | (vb0.x << 16);
        *(unsigned int*)&Vt[nb][s_dg*4+1][s_kp]    = (va0.x >> 16)     | (vb0.x & 0xffff0000u);
        *(unsigned int*)&Vt[nb][s_dg*4+2][s_kp]    = (va0.y & 0xffffu) | (vb0.y << 16);
        *(unsigned int*)&Vt[nb][s_dg*4+3][s_kp]    = (va0.y >> 16)     | (vb0.y & 0xffff0000u);
        *(unsigned int*)&Vt[nb][s_dg*4+0][s_kp+32] = (va1.x & 0xffffu) | (vb1.x << 16);
        *(unsigned int*)&Vt[nb][s_dg*4+1][s_kp+32] = (va1.x >> 16)     | (vb1.x & 0xffff0000u);
        *(unsigned int*)&Vt[nb][s_dg*4+2][s_kp+32] = (va1.y & 0xffffu) | (vb1.y << 16);
        *(unsigned int*)&Vt[nb][s_dg*4+3][s_kp+32] = (va1.y >> 16)     | (vb1.y & 0xffff0000u);
    };

    int qrow0 = qtA*64 + wv*16;
    bf16x8 q0 = *(const bf16x8*)&Qbh[(size_t)(qrow0 + ln)*HD + lg*8];
    bf16x8 q1 = *(const bf16x8*)&Qbh[(size_t)(qrow0 + ln)*HD + 32 + lg*8];

    f32x4 o[4] = {};
    float m[4], lsum[4];
    #pragma unroll
    for (int r = 0; r < 4; ++r) { m[r] = -1e30f; lsum[r] = 0.f; }

    auto epilogue = [&](int qr0) {
        const int bb = bh >> 4;
        const int h  = bh & 15;
        #pragma unroll
        for (int r = 0; r < 4; ++r) {
            const float inv = 1.f / lsum[r];
            const size_t rowoff = ((size_t)bb*SEQ + qr0 + lg*4 + r)*D_MODEL + h*HD;
            #pragma unroll
            for (int f = 0; f < 4; ++f)
                AO[rowoff + f*16 + ln] = f2bf(o[f][r] * inv);
        }
    };

    stage(0, 0);

    for (int t = 0; t < nT; ++t) {
        __syncthreads();
        const int buf = t & 1;
        if (t + 1 < nT)
            stage(buf ^ 1, (t + 1 < nTA ? t + 1 : t + 1 - nTA) * 64);
        const int kt = (t < nTA ? t : t - nTA) * 64;

        // ---- QK^T: S(16 x 64 keys), 4 key-groups x 2 k-chunks
        f32x4 s[4];
        #pragma unroll
        for (int g = 0; g < 4; ++g) {
            bf16x8 ka = *(const bf16x8*)&Ks[buf][g*16 + ln][lg*8];
            bf16x8 kb = *(const bf16x8*)&Ks[buf][g*16 + ln][32 + lg*8];
            f32x4 sg = {};
            sg = __builtin_amdgcn_mfma_f32_16x16x32_bf16(q0, ka, sg, 0, 0, 0);
            sg = __builtin_amdgcn_mfma_f32_16x16x32_bf16(q1, kb, sg, 0, 0, 0);
            s[g] = sg;
        }

        // ---- scale + causal mask + in-lane max over the 4 key-groups
        float mt[4];
        #pragma unroll
        for (int r = 0; r < 4; ++r) {
            const int qg = qrow0 + lg*4 + r;
            float mx = -1e30f;
            #pragma unroll
            for (int g = 0; g < 4; ++g) {
                float v = s[g][r] * 0.125f;
                v = (kt + g*16 + ln > qg) ? -1e30f : v;
                s[g][r] = v;
                mx = fmaxf(mx, v);
            }
            mt[r] = mx;
        }
        // one 4-level butterfly over the 16 n-lanes
        #pragma unroll
        for (int d = 1; d <= 8; d <<= 1) {
            #pragma unroll
            for (int r = 0; r < 4; ++r) mt[r] = fmaxf(mt[r], __shfl_xor(mt[r], d));
        }
        float alpha[4], ps[4];
        #pragma unroll
        for (int r = 0; r < 4; ++r) {
            const float mnew = fmaxf(m[r], mt[r]);
            alpha[r] = __expf(m[r] - mnew);
            m[r] = mnew;
            float sum = 0.f;
            #pragma unroll
            for (int g = 0; g < 4; ++g) {
                const float e = __expf(s[g][r] - mnew);
                s[g][r] = e;
                sum += e;
            }
            ps[r] = sum;
        }
        #pragma unroll
        for (int d = 1; d <= 8; d <<= 1) {
            #pragma unroll
            for (int r = 0; r < 4; ++r) ps[r] += __shfl_xor(ps[r], d);
        }
        #pragma unroll
        for (int r = 0; r < 4; ++r) {
            lsum[r] = lsum[r]*alpha[r] + ps[r];
            #pragma unroll
            for (int f = 0; f < 4; ++f) o[f][r] *= alpha[r];
        }

        // ---- P -> LDS (C-layout), re-read as A-layout (two 32-key halves)
        #pragma unroll
        for (int r = 0; r < 4; ++r)
            #pragma unroll
            for (int g = 0; g < 4; ++g)
                Pl[wv][lg*4 + r][g*16 + ln] = f2bf(s[g][r]);
        bf16x8 pa0 = *(const bf16x8*)&Pl[wv][ln][lg*8];
        bf16x8 pa1 = *(const bf16x8*)&Pl[wv][ln][32 + lg*8];

        // ---- PV: O(16 x 64) += P(16x64) * V(64x64)
        #pragma unroll
        for (int f = 0; f < 4; ++f) {
            bf16x8 v0 = *(const bf16x8*)&Vt[buf][f*16 + ln][lg*8];
            bf16x8 v1 = *(const bf16x8*)&Vt[buf][f*16 + ln][32 + lg*8];
            o[f] = __builtin_amdgcn_mfma_f32_16x16x32_bf16(pa0, v0, o[f], 0, 0, 0);
            o[f] = __builtin_amdgcn_mfma_f32_16x16x32_bf16(pa1, v1, o[f], 0, 0, 0);
        }

        // ---- phase boundary: flush q-tile A, reset for q-tile B
        if (t == nTA - 1) {
            epilogue(qrow0);
            qrow0 = qtB*64 + wv*16;
            q0 = *(const bf16x8*)&Qbh[(size_t)(qrow0 + ln)*HD + lg*8];
            q1 = *(const bf16x8*)&Qbh[(size_t)(qrow0 + ln)*HD + 32 + lg*8];
            #pragma unroll
            for (int r = 0; r < 4; ++r) {
                m[r] = -1e30f; lsum[r] = 0.f;
                #pragma unroll
                for (int f = 0; f < 4; ++f) o[f][r] = 0.f;
            }
        }
    }
    epilogue(qrow0);   // q-tile B
}

// ---------------------------------------------------------------------------
extern "C" void kernel_launch(void* const* d_in, const int* in_sizes, int n_in,
                              void* d_out, int out_size, void* d_ws, size_t ws_size,
                              hipStream_t stream)
{
    const float* x     = (const float*)d_in[0];   // (2,2048,1024)
    const float* w_qkv = (const float*)d_in[1];   // (1024,3072)
    const float* w_out = (const float*)d_in[2];   // (1024,1024)
    float* out = (float*)d_out;                   // (2,2048,1024)

    const size_t nX  = (size_t)BATCH*SEQ*D_MODEL;
    const size_t nWq = (size_t)D_MODEL*3*D_MODEL;
    const size_t nWo = (size_t)D_MODEL*D_MODEL;
    const size_t per = (size_t)BH * SEQ * HD;

    unsigned short* Xb  = (unsigned short*)d_ws;
    unsigned short* Wqb = Xb  + nX;
    unsigned short* Wob = Wqb + nWq;
    unsigned short* Qb  = Wob + nWo;
    unsigned short* Kb  = Qb + per;
    unsigned short* Vb  = Kb + per;
    unsigned short* AOb = Vb + per;

    cvt3_kernel<<<1024, 256, 0, stream>>>(
        x, (int)(nX/8), w_qkv, (int)(nWq/8), w_out, (int)(nWo/8), Xb);

    gemm_bf16_kernel<3*D_MODEL, true><<<dim3(24, 32), 256, 0, stream>>>(
        Xb, Wqb, Qb, Kb, Vb, nullptr);
    // causal attention: paired q-tiles, grid = (16, 32) = 512 blocks
    attn_kernel<<<dim3(16, BH), 256, 0, stream>>>(Qb, Kb, Vb, AOb);
    gemm_bf16_kernel<D_MODEL, false><<<dim3(8, 32), 256, 0, stream>>>(
        AOb, Wob, nullptr, nullptr, nullptr, out);
}

// Round 14
// 160.286 us; speedup vs baseline: 9.9716x; 1.0874x over previous
//
#include <hip/hip_runtime.h>
#include <hip/hip_bf16.h>
#include <cstddef>

#define D_MODEL 1024
#define NHEAD   16
#define HD      64
#define BATCH   2
#define SEQ     2048
#define BH      (BATCH*NHEAD)   // 32

typedef short bf16x8 __attribute__((ext_vector_type(8)));
typedef unsigned short u16x8 __attribute__((ext_vector_type(8)));
typedef float f32x4  __attribute__((ext_vector_type(4)));

static __device__ __forceinline__ unsigned short f2bf(float f) {
    __hip_bfloat16 h = __float2bfloat16(f);   // RNE
    return __builtin_bit_cast(unsigned short, h);
}
static __device__ __forceinline__ unsigned int pk2(float a, float b) {
    return (unsigned int)f2bf(a) | ((unsigned int)f2bf(b) << 16);
}

// ---------------------------------------------------------------------------
// K0: fp32 -> bf16 for x, w_qkv, w_out in ONE launch (dst contiguous in ws).
// ---------------------------------------------------------------------------
__global__ __launch_bounds__(256) void cvt3_kernel(
    const float* __restrict__ a, int na8,
    const float* __restrict__ b, int nb8,
    const float* __restrict__ c, int nc8,
    unsigned short* __restrict__ dst)
{
    const int tot = na8 + nb8 + nc8;
    const int stride = gridDim.x * blockDim.x;
    for (int i = blockIdx.x*blockDim.x + threadIdx.x; i < tot; i += stride) {
        const float* s; int off;
        if (i < na8)            { s = a; off = i; }
        else if (i < na8 + nb8) { s = b; off = i - na8; }
        else                    { s = c; off = i - na8 - nb8; }
        const float4 p = ((const float4*)s)[off*2];
        const float4 q = ((const float4*)s)[off*2+1];
        uint4 w;
        w.x = pk2(p.x, p.y); w.y = pk2(p.z, p.w);
        w.z = pk2(q.x, q.y); w.w = pk2(q.z, q.w);
        ((uint4*)dst)[i] = w;
    }
}

// ---------------------------------------------------------------------------
// K1/K3: bf16 MFMA GEMM, C = A(M x 1024) * B(1024 x NN). Unchanged (R10).
// ---------------------------------------------------------------------------
template<int NN, bool QKV>
__global__ __launch_bounds__(256, 2) void gemm_bf16_kernel(
    const unsigned short* __restrict__ A, const unsigned short* __restrict__ B,
    unsigned short* __restrict__ Qo, unsigned short* __restrict__ Ko,
    unsigned short* __restrict__ Vo, float* __restrict__ Cf)
{
    __shared__ __align__(16) unsigned short As[128][44];
    __shared__ __align__(16) unsigned short Bs[128][44];

    const int tid  = threadIdx.x;
    const int wv   = tid >> 6;
    const int l    = tid & 63;
    const int ln   = l & 15;
    const int lg   = l >> 4;
    const int wrow = (wv >> 1) * 64;
    const int wcol = (wv & 1) * 64;
    const int mtile = blockIdx.y * 128;
    const int ntile = blockIdx.x * 128;

    const int a_r  = tid >> 2;
    const int a_k  = (tid & 3) * 8;
    const int b_kp = tid >> 4;
    const int b_ng = tid & 15;

    f32x4 acc[4][4] = {};

    for (int kb = 0; kb < 32; ++kb) {
        const unsigned short* Ag = A + (size_t)(mtile + a_r)*1024 + kb*32 + a_k;
        *(uint4*)&As[a_r     ][a_k] = *(const uint4*)Ag;
        *(uint4*)&As[a_r + 64][a_k] = *(const uint4*)(Ag + (size_t)64*1024);
        {
            const int kk = kb*32 + b_kp*2;
            const int nn = ntile + b_ng*8;
            uint4 r0 = *(const uint4*)&B[(size_t)kk*NN + nn];
            uint4 r1 = *(const uint4*)&B[(size_t)(kk+1)*NN + nn];
            u16x8 x0 = __builtin_bit_cast(u16x8, r0);
            u16x8 x1 = __builtin_bit_cast(u16x8, r1);
            #pragma unroll
            for (int j = 0; j < 8; ++j)
                *(unsigned int*)&Bs[b_ng*8 + j][b_kp*2] =
                    (unsigned int)x0[j] | ((unsigned int)x1[j] << 16);
        }
        __syncthreads();
        bf16x8 af[4], bf[4];
        #pragma unroll
        for (int i = 0; i < 4; ++i)
            af[i] = *(const bf16x8*)&As[wrow + i*16 + ln][lg*8];
        #pragma unroll
        for (int j = 0; j < 4; ++j)
            bf[j] = *(const bf16x8*)&Bs[wcol + j*16 + ln][lg*8];
        #pragma unroll
        for (int i = 0; i < 4; ++i)
            #pragma unroll
            for (int j = 0; j < 4; ++j)
                acc[i][j] = __builtin_amdgcn_mfma_f32_16x16x32_bf16(af[i], bf[j], acc[i][j], 0, 0, 0);
        __syncthreads();
    }

    #pragma unroll
    for (int i = 0; i < 4; ++i) {
        #pragma unroll
        for (int r = 0; r < 4; ++r) {
            const int mm = mtile + wrow + i*16 + lg*4 + r;
            if constexpr (QKV) {
                const int bb = mm >> 11;
                const int ss = mm & 2047;
                #pragma unroll
                for (int j = 0; j < 4; ++j) {
                    const int cb  = ntile + wcol + j*16 + ln;
                    const int wch = cb >> 10;
                    const int rem = cb & 1023;
                    const int h   = rem >> 6;
                    const int dd  = rem & 63;
                    unsigned short* dstBase = (wch == 0) ? Qo : (wch == 1) ? Ko : Vo;
                    dstBase[((size_t)(bb*NHEAD + h)*SEQ + ss)*HD + dd] = f2bf(acc[i][j][r]);
                }
            } else {
                #pragma unroll
                for (int j = 0; j < 4; ++j) {
                    const int cb = ntile + wcol + j*16 + ln;
                    Cf[(size_t)mm*NN + cb] = acc[i][j][r];
                }
            }
        }
    }
}

// ---------------------------------------------------------------------------
// K2 v9: causal flash attention with SWAPPED QK^T (S^T = mfma(K,Q)).
// Same geometry as v8 (KVBLK=64, paired q-tiles qtA=31-bx / qtB=bx, 33 key-
// tiles per block, grid (16,32)). Swap makes q-row ownership lane-local:
//   S^T D-layout: q-row = ln, key = 16g + 4*lg + r  ->  m,l are per-lane
//   SCALARS; row reduce = in-lane(16) + shfl_xor(16,32) [2 levels vs 4].
// P^T pack: 4 ds_write_b64 (contiguous) -> read 2 b128 as PV B-frags.
// PV: O^T = mfma(A=V^T, B=P^T); V^T-frags read from Vt exactly as v8.
// o[f][r]: q-row = ln, d = f*16 + lg*4 + r. Epilogue: 4x 8B stores.
// Defer-max (T13): skip alpha/rescale when __any(mx>m) is false (safe:
// skip only when new tile max <= running max, so P<=1).
// ---------------------------------------------------------------------------
__global__ __launch_bounds__(256, 2) void attn_kernel(
    const unsigned short* __restrict__ Qb, const unsigned short* __restrict__ Kb,
    const unsigned short* __restrict__ Vb, unsigned short* __restrict__ AO)
{
    __shared__ __align__(16) unsigned short Ks[2][64][72];  // keys x dims(+pad)
    __shared__ __align__(16) unsigned short Vt[2][64][72];  // dims x keys(+pad)
    __shared__ __align__(16) unsigned short Pl[4][16][76];  // per-wave P^T 16q x 64k

    const int tid = threadIdx.x;
    const int wv  = tid >> 6;
    const int l   = tid & 63;
    const int ln  = l & 15;
    const int lg  = l >> 4;
    const int bh  = blockIdx.y;
    const int bx  = blockIdx.x;          // 0..15
    const int qtA = 31 - bx;
    const int qtB = bx;
    const int nTA = qtA + 1;
    const int nT  = nTA + qtB + 1;       // 33 always

    const unsigned short* Qbh = Qb + (size_t)bh*SEQ*HD;
    const unsigned short* Kbh = Kb + (size_t)bh*SEQ*HD;
    const unsigned short* Vbh = Vb + (size_t)bh*SEQ*HD;

    // staging indices
    const int s_kl = tid >> 3;            // key 0..31 (and +32)
    const int s_d0 = (tid & 7) << 3;      // dim0
    const int s_dg = tid >> 4;            // dim group 0..15
    const int s_kp = (tid & 15) << 1;     // key pair (and +32)

    auto stage = [&](int nb, int kt) {
        *(uint4*)&Ks[nb][s_kl     ][s_d0] = *(const uint4*)&Kbh[(size_t)(kt + s_kl     )*HD + s_d0];
        *(uint4*)&Ks[nb][s_kl + 32][s_d0] = *(const uint4*)&Kbh[(size_t)(kt + s_kl + 32)*HD + s_d0];
        uint2 va0 = *(const uint2*)&Vbh[(size_t)(kt + s_kp     )*HD + s_dg*4];
        uint2 vb0 = *(const uint2*)&Vbh[(size_t)(kt + s_kp + 1 )*HD + s_dg*4];
        uint2 va1 = *(const uint2*)&Vbh[(size_t)(kt + s_kp + 32)*HD + s_dg*4];
        uint2 vb1 = *(const uint2*)&Vbh[(size_t)(kt + s_kp + 33)*HD + s_dg*4];
        *(unsigned int*)&Vt[nb][s_dg*4+0][s_kp]    = (va0.x & 0xffffu) | (vb0.x << 16);
        *(unsigned int*)&Vt[nb][s_dg*4+1][s_kp]    = (va0.x >> 16)     | (vb0.x & 0xffff0000u);
        *(unsigned int*)&Vt[nb][s_dg*4+2][s_kp]    = (va0.y & 0xffffu) | (vb0.y << 16);
        *(unsigned int*)&Vt[nb][s_dg*4+3][s_kp]    = (va0.y >> 16)     | (vb0.y & 0xffff0000u);
        *(unsigned int*)&Vt[nb][s_dg*4+0][s_kp+32] = (va1.x & 0xffffu) | (vb1.x << 16);
        *(unsigned int*)&Vt[nb][s_dg*4+1][s_kp+32] = (va1.x >> 16)     | (vb1.x & 0xffff0000u);
        *(unsigned int*)&Vt[nb][s_dg*4+2][s_kp+32] = (va1.y & 0xffffu) | (vb1.y << 16);
        *(unsigned int*)&Vt[nb][s_dg*4+3][s_kp+32] = (va1.y >> 16)     | (vb1.y & 0xffff0000u);
    };

    int qrow0 = qtA*64 + wv*16;
    // Q as B-frag: lane ln = q-row, dims lg*8..+7 (and +32)
    bf16x8 q0 = *(const bf16x8*)&Qbh[(size_t)(qrow0 + ln)*HD + lg*8];
    bf16x8 q1 = *(const bf16x8*)&Qbh[(size_t)(qrow0 + ln)*HD + 32 + lg*8];

    f32x4 o[4] = {};               // o[f][r]: d = f*16+lg*4+r, q-row = ln
    float m = -1e30f, lsum = 0.f;  // per-lane scalars (q-row = ln)

    auto epilogue = [&](int qr0) {
        const int bb = bh >> 4;
        const int h  = bh & 15;
        const float inv = 1.f / lsum;
        const size_t base = ((size_t)bb*SEQ + qr0 + ln)*D_MODEL + h*HD + lg*4;
        #pragma unroll
        for (int f = 0; f < 4; ++f) {
            uint2 w;
            w.x = pk2(o[f][0]*inv, o[f][1]*inv);
            w.y = pk2(o[f][2]*inv, o[f][3]*inv);
            *(uint2*)&AO[base + f*16] = w;
        }
    };

    stage(0, 0);

    for (int t = 0; t < nT; ++t) {
        __syncthreads();
        const int buf = t & 1;
        if (t + 1 < nT)
            stage(buf ^ 1, (t + 1 < nTA ? t + 1 : t + 1 - nTA) * 64);
        const int kt = (t < nTA ? t : t - nTA) * 64;

        // ---- QK^T swapped: S^T(64keys x 16q), K as A-frag, Q as B-frag
        f32x4 s[4];
        #pragma unroll
        for (int g = 0; g < 4; ++g) {
            bf16x8 ka = *(const bf16x8*)&Ks[buf][g*16 + ln][lg*8];
            bf16x8 kb = *(const bf16x8*)&Ks[buf][g*16 + ln][32 + lg*8];
            f32x4 sg = {};
            sg = __builtin_amdgcn_mfma_f32_16x16x32_bf16(ka, q0, sg, 0, 0, 0);
            sg = __builtin_amdgcn_mfma_f32_16x16x32_bf16(kb, q1, sg, 0, 0, 0);
            s[g] = sg;
        }

        // ---- scale + causal mask (key = kt+16g+4lg+r vs q-row qrow0+ln)
        const int qg = qrow0 + ln;
        const int kbase = kt + lg*4;
        float mx = -1e30f;
        #pragma unroll
        for (int g = 0; g < 4; ++g) {
            #pragma unroll
            for (int r = 0; r < 4; ++r) {
                float v = s[g][r] * 0.125f;
                v = (kbase + g*16 + r > qg) ? -1e30f : v;
                s[g][r] = v;
                mx = fmaxf(mx, v);
            }
        }
        // row reduce: 2 levels (lanes ln, ln+16, ln+32, ln+48)
        mx = fmaxf(mx, __shfl_xor(mx, 16));
        mx = fmaxf(mx, __shfl_xor(mx, 32));

        // ---- defer-max: rescale only if the running max grew anywhere
        if (__any(mx > m)) {
            const float mnew = fmaxf(m, mx);
            const float alpha = __expf(m - mnew);
            m = mnew;
            lsum *= alpha;
            #pragma unroll
            for (int f = 0; f < 4; ++f)
                #pragma unroll
                for (int r = 0; r < 4; ++r) o[f][r] *= alpha;
        }
        float ps = 0.f;
        #pragma unroll
        for (int g = 0; g < 4; ++g) {
            #pragma unroll
            for (int r = 0; r < 4; ++r) {
                const float e = __expf(s[g][r] - m);
                s[g][r] = e;
                ps += e;
            }
        }
        ps += __shfl_xor(ps, 16);
        ps += __shfl_xor(ps, 32);
        lsum += ps;

        // ---- P^T -> LDS: Pl[ln][key] via 4 contiguous b64 writes
        #pragma unroll
        for (int g = 0; g < 4; ++g) {
            unsigned long long w =
                (unsigned long long)pk2(s[g][0], s[g][1]) |
                ((unsigned long long)pk2(s[g][2], s[g][3]) << 32);
            *(unsigned long long*)&Pl[wv][ln][g*16 + lg*4] = w;
        }
        // PV B-frags: keys lg*8..+7 (and +32) for q-col ln
        bf16x8 pb0 = *(const bf16x8*)&Pl[wv][ln][lg*8];
        bf16x8 pb1 = *(const bf16x8*)&Pl[wv][ln][32 + lg*8];

        // ---- PV swapped: O^T(64d x 16q) += V^T(d x k) * P^T(k x q)
        #pragma unroll
        for (int f = 0; f < 4; ++f) {
            bf16x8 v0 = *(const bf16x8*)&Vt[buf][f*16 + ln][lg*8];
            bf16x8 v1 = *(const bf16x8*)&Vt[buf][f*16 + ln][32 + lg*8];
            o[f] = __builtin_amdgcn_mfma_f32_16x16x32_bf16(v0, pb0, o[f], 0, 0, 0);
            o[f] = __builtin_amdgcn_mfma_f32_16x16x32_bf16(v1, pb1, o[f], 0, 0, 0);
        }

        // ---- phase boundary: flush q-tile A, reset for q-tile B
        if (t == nTA - 1) {
            epilogue(qrow0);
            qrow0 = qtB*64 + wv*16;
            q0 = *(const bf16x8*)&Qbh[(size_t)(qrow0 + ln)*HD + lg*8];
            q1 = *(const bf16x8*)&Qbh[(size_t)(qrow0 + ln)*HD + 32 + lg*8];
            m = -1e30f; lsum = 0.f;
            #pragma unroll
            for (int f = 0; f < 4; ++f)
                #pragma unroll
                for (int r = 0; r < 4; ++r) o[f][r] = 0.f;
        }
    }
    epilogue(qrow0);   // q-tile B
}

// ---------------------------------------------------------------------------
extern "C" void kernel_launch(void* const* d_in, const int* in_sizes, int n_in,
                              void* d_out, int out_size, void* d_ws, size_t ws_size,
                              hipStream_t stream)
{
    const float* x     = (const float*)d_in[0];   // (2,2048,1024)
    const float* w_qkv = (const float*)d_in[1];   // (1024,3072)
    const float* w_out = (const float*)d_in[2];   // (1024,1024)
    float* out = (float*)d_out;                   // (2,2048,1024)

    const size_t nX  = (size_t)BATCH*SEQ*D_MODEL;
    const size_t nWq = (size_t)D_MODEL*3*D_MODEL;
    const size_t nWo = (size_t)D_MODEL*D_MODEL;
    const size_t per = (size_t)BH * SEQ * HD;

    unsigned short* Xb  = (unsigned short*)d_ws;
    unsigned short* Wqb = Xb  + nX;
    unsigned short* Wob = Wqb + nWq;
    unsigned short* Qb  = Wob + nWo;
    unsigned short* Kb  = Qb + per;
    unsigned short* Vb  = Kb + per;
    unsigned short* AOb = Vb + per;

    cvt3_kernel<<<1024, 256, 0, stream>>>(
        x, (int)(nX/8), w_qkv, (int)(nWq/8), w_out, (int)(nWo/8), Xb);

    gemm_bf16_kernel<3*D_MODEL, true><<<dim3(24, 32), 256, 0, stream>>>(
        Xb, Wqb, Qb, Kb, Vb, nullptr);
    // causal attention: paired q-tiles, grid = (16, 32) = 512 blocks
    attn_kernel<<<dim3(16, BH), 256, 0, stream>>>(Qb, Kb, Vb, AOb);
    gemm_bf16_kernel<D_MODEL, false><<<dim3(8, 32), 256, 0, stream>>>(
        AOb, Wob, nullptr, nullptr, nullptr, out);
}

// Round 15
// 136.009 us; speedup vs baseline: 11.7516x; 1.1785x over previous
//
#include <hip/hip_runtime.h>
#include <hip/hip_bf16.h>
#include <cstddef>

#define D_MODEL 1024
#define NHEAD   16
#define HD      64
#define BATCH   2
#define SEQ     2048
#define BH      (BATCH*NHEAD)   // 32

typedef short bf16x8 __attribute__((ext_vector_type(8)));
typedef float f32x4  __attribute__((ext_vector_type(4)));

static __device__ __forceinline__ unsigned short f2bf(float f) {
    __hip_bfloat16 h = __float2bfloat16(f);   // RNE
    return __builtin_bit_cast(unsigned short, h);
}
static __device__ __forceinline__ unsigned int pk2(float a, float b) {
    return (unsigned int)f2bf(a) | ((unsigned int)f2bf(b) << 16);
}

// global -> LDS async DMA, 16B per lane: LDS dest = uniform base + lane*16.
#define GLD16(gp, lp) __builtin_amdgcn_global_load_lds( \
    (const __attribute__((address_space(1))) unsigned int*)(gp), \
    (__attribute__((address_space(3))) unsigned int*)(lp), 16, 0, 0)

// ---------------------------------------------------------------------------
// K0a: fp32 -> bf16 linear (x only). 8 elems/thread, grid-stride.
// ---------------------------------------------------------------------------
__global__ __launch_bounds__(256) void cvt_kernel(
    const float* __restrict__ src, unsigned short* __restrict__ dst, int n8)
{
    const int stride = gridDim.x * blockDim.x;
    for (int i = blockIdx.x*blockDim.x + threadIdx.x; i < n8; i += stride) {
        const float4 a = ((const float4*)src)[i*2];
        const float4 b = ((const float4*)src)[i*2+1];
        uint4 w;
        w.x = pk2(a.x, a.y); w.y = pk2(a.z, a.w);
        w.z = pk2(b.x, b.y); w.w = pk2(b.z, b.w);
        ((uint4*)dst)[i] = w;
    }
}

// ---------------------------------------------------------------------------
// K0b: fp32 (K x N) -> bf16 TRANSPOSED (N x K) for both weights, one launch.
// 32x32 tiles via LDS. bx<96: w_qkv (N=3072); else: w_out (N=1024).
// ---------------------------------------------------------------------------
__global__ __launch_bounds__(256) void cvt_tr_kernel(
    const float* __restrict__ Wq, const float* __restrict__ Wo,
    unsigned short* __restrict__ WqT, unsigned short* __restrict__ WoT)
{
    __shared__ float T[32][33];
    const int tid = threadIdx.x;
    const int bx  = blockIdx.x;       // n-tile
    const int k0  = blockIdx.y * 32;  // k-tile
    const float* W; unsigned short* WT; int N, n0;
    if (bx < 96) { W = Wq; WT = WqT; N = 3072; n0 = bx*32; }
    else         { W = Wo; WT = WoT; N = 1024; n0 = (bx-96)*32; }
    const int r  = tid >> 3;          // 0..31
    const int cg = tid & 7;           // 0..7
    float4 v = *(const float4*)&W[(size_t)(k0 + r)*N + n0 + cg*4];
    T[r][cg*4+0] = v.x; T[r][cg*4+1] = v.y;
    T[r][cg*4+2] = v.z; T[r][cg*4+3] = v.w;
    __syncthreads();
    uint2 w;
    w.x = pk2(T[cg*4+0][r], T[cg*4+1][r]);
    w.y = pk2(T[cg*4+2][r], T[cg*4+3][r]);
    *(uint2*)&WT[(size_t)(n0 + r)*1024 + k0 + cg*4] = w;
}

// ---------------------------------------------------------------------------
// K1/K3 v2: bf16 MFMA GEMM, C = A(M x 1024) * B(1024 x NN), B given as
// B^T (NN x 1024, k-major). BOTH operands staged via global_load_lds w=16
// (ladder step 3: the 517->874 TF lever). LDS linear [128][32] (padding
// would break gload_lds, m173). Bank fix per rule #21 (both-sides):
// source chunk kc ^= f(r), read chunk lg ^= f(R), f(r)=(r+(r>>2))&3 ->
// perfect 2-way spread on ds_read_b128 (free, m136); f(R) folds to the
// per-lane constant (ln+(ln>>2))&3 since wrow,i*16 are 0 mod 4 after >>2.
// Fragment layouts unchanged (m89-verified) -> bit-exact vs R10 GEMM.
// ---------------------------------------------------------------------------
template<int NN, bool QKV>
__global__ __launch_bounds__(256, 2) void gemm_bf16_kernel(
    const unsigned short* __restrict__ A, const unsigned short* __restrict__ BT,
    unsigned short* __restrict__ Qo, unsigned short* __restrict__ Ko,
    unsigned short* __restrict__ Vo, float* __restrict__ Cf)
{
    __shared__ __align__(16) unsigned short As[128*32];
    __shared__ __align__(16) unsigned short Bs[128*32];

    const int tid  = threadIdx.x;
    const int wv   = tid >> 6;
    const int l    = tid & 63;
    const int ln   = l & 15;
    const int lg   = l >> 4;
    const int wrow = (wv >> 1) * 64;
    const int wcol = (wv & 1) * 64;
    const int mtile = blockIdx.y * 128;
    const int ntile = blockIdx.x * 128;

    // staging: 16B chunk c = wv*128 + t*64 + l (t=0,1); row r=c>>2, kc=c&3;
    // source chunk = kc ^ f(r).
    const int c0 = wv*128 + l;
    const int c1 = c0 + 64;
    const int r0 = c0 >> 2, ks0 = ((c0 & 3) ^ ((r0 + (r0 >> 2)) & 3)) * 8;
    const int r1 = c1 >> 2, ks1 = ((c1 & 3) ^ ((r1 + (r1 >> 2)) & 3)) * 8;
    const size_t gA0 = (size_t)(mtile + r0)*1024 + ks0;
    const size_t gA1 = (size_t)(mtile + r1)*1024 + ks1;
    const size_t gB0 = (size_t)(ntile + r0)*1024 + ks0;
    const size_t gB1 = (size_t)(ntile + r1)*1024 + ks1;
    unsigned short* lA0 = &As[(wv*128     ) * 8];
    unsigned short* lA1 = &As[(wv*128 + 64) * 8];
    unsigned short* lB0 = &Bs[(wv*128     ) * 8];
    unsigned short* lB1 = &Bs[(wv*128 + 64) * 8];

    // read-side swizzle: chunk = lg ^ ((ln + (ln>>2)) & 3)
    const int sw = ((lg ^ ((ln + (ln >> 2)) & 3))) * 8;

    f32x4 acc[4][4] = {};

    for (int kb = 0; kb < 32; ++kb) {
        const int koff = kb * 32;
        GLD16(A  + gA0 + koff, lA0);
        GLD16(A  + gA1 + koff, lA1);
        GLD16(BT + gB0 + koff, lB0);
        GLD16(BT + gB1 + koff, lB1);
        __syncthreads();                       // drains vmcnt, publishes LDS
        bf16x8 af[4], bf[4];
        #pragma unroll
        for (int i = 0; i < 4; ++i)
            af[i] = *(const bf16x8*)&As[(wrow + i*16 + ln)*32 + sw];
        #pragma unroll
        for (int j = 0; j < 4; ++j)
            bf[j] = *(const bf16x8*)&Bs[(wcol + j*16 + ln)*32 + sw];
        #pragma unroll
        for (int i = 0; i < 4; ++i)
            #pragma unroll
            for (int j = 0; j < 4; ++j)
                acc[i][j] = __builtin_amdgcn_mfma_f32_16x16x32_bf16(af[i], bf[j], acc[i][j], 0, 0, 0);
        __syncthreads();                       // protect LDS before next stage
    }

    #pragma unroll
    for (int i = 0; i < 4; ++i) {
        #pragma unroll
        for (int r = 0; r < 4; ++r) {
            const int mm = mtile + wrow + i*16 + lg*4 + r;
            if constexpr (QKV) {
                const int bb = mm >> 11;
                const int ss = mm & 2047;
                #pragma unroll
                for (int j = 0; j < 4; ++j) {
                    const int cb  = ntile + wcol + j*16 + ln;
                    const int wch = cb >> 10;
                    const int rem = cb & 1023;
                    const int h   = rem >> 6;
                    const int dd  = rem & 63;
                    unsigned short* dstBase = (wch == 0) ? Qo : (wch == 1) ? Ko : Vo;
                    dstBase[((size_t)(bb*NHEAD + h)*SEQ + ss)*HD + dd] = f2bf(acc[i][j][r]);
                }
            } else {
                #pragma unroll
                for (int j = 0; j < 4; ++j) {
                    const int cb = ntile + wcol + j*16 + ln;
                    Cf[(size_t)mm*NN + cb] = acc[i][j][r];
                }
            }
        }
    }
}

// ---------------------------------------------------------------------------
// K2 v9: causal flash attention with SWAPPED QK^T. Unchanged from R14
// (passing, 71 us, absmax .0156).
// ---------------------------------------------------------------------------
__global__ __launch_bounds__(256, 2) void attn_kernel(
    const unsigned short* __restrict__ Qb, const unsigned short* __restrict__ Kb,
    const unsigned short* __restrict__ Vb, unsigned short* __restrict__ AO)
{
    __shared__ __align__(16) unsigned short Ks[2][64][72];  // keys x dims(+pad)
    __shared__ __align__(16) unsigned short Vt[2][64][72];  // dims x keys(+pad)
    __shared__ __align__(16) unsigned short Pl[4][16][76];  // per-wave P^T 16q x 64k

    const int tid = threadIdx.x;
    const int wv  = tid >> 6;
    const int l   = tid & 63;
    const int ln  = l & 15;
    const int lg  = l >> 4;
    const int bh  = blockIdx.y;
    const int bx  = blockIdx.x;          // 0..15
    const int qtA = 31 - bx;
    const int qtB = bx;
    const int nTA = qtA + 1;
    const int nT  = nTA + qtB + 1;       // 33 always

    const unsigned short* Qbh = Qb + (size_t)bh*SEQ*HD;
    const unsigned short* Kbh = Kb + (size_t)bh*SEQ*HD;
    const unsigned short* Vbh = Vb + (size_t)bh*SEQ*HD;

    const int s_kl = tid >> 3;
    const int s_d0 = (tid & 7) << 3;
    const int s_dg = tid >> 4;
    const int s_kp = (tid & 15) << 1;

    auto stage = [&](int nb, int kt) {
        *(uint4*)&Ks[nb][s_kl     ][s_d0] = *(const uint4*)&Kbh[(size_t)(kt + s_kl     )*HD + s_d0];
        *(uint4*)&Ks[nb][s_kl + 32][s_d0] = *(const uint4*)&Kbh[(size_t)(kt + s_kl + 32)*HD + s_d0];
        uint2 va0 = *(const uint2*)&Vbh[(size_t)(kt + s_kp     )*HD + s_dg*4];
        uint2 vb0 = *(const uint2*)&Vbh[(size_t)(kt + s_kp + 1 )*HD + s_dg*4];
        uint2 va1 = *(const uint2*)&Vbh[(size_t)(kt + s_kp + 32)*HD + s_dg*4];
        uint2 vb1 = *(const uint2*)&Vbh[(size_t)(kt + s_kp + 33)*HD + s_dg*4];
        *(unsigned int*)&Vt[nb][s_dg*4+0][s_kp]    = (va0.x & 0xffffu) | (vb0.x << 16);
        *(unsigned int*)&Vt[nb][s_dg*4+1][s_kp]    = (va0.x >> 16)     | (vb0.x & 0xffff0000u);
        *(unsigned int*)&Vt[nb][s_dg*4+2][s_kp]    = (va0.y & 0xffffu) | (vb0.y << 16);
        *(unsigned int*)&Vt[nb][s_dg*4+3][s_kp]    = (va0.y >> 16)     | (vb0.y & 0xffff0000u);
        *(unsigned int*)&Vt[nb][s_dg*4+0][s_kp+32] = (va1.x & 0xffffu) | (vb1.x << 16);
        *(unsigned int*)&Vt[nb][s_dg*4+1][s_kp+32] = (va1.x >> 16)     | (vb1.x & 0xffff0000u);
        *(unsigned int*)&Vt[nb][s_dg*4+2][s_kp+32] = (va1.y & 0xffffu) | (vb1.y << 16);
        *(unsigned int*)&Vt[nb][s_dg*4+3][s_kp+32] = (va1.y >> 16)     | (vb1.y & 0xffff0000u);
    };

    int qrow0 = qtA*64 + wv*16;
    bf16x8 q0 = *(const bf16x8*)&Qbh[(size_t)(qrow0 + ln)*HD + lg*8];
    bf16x8 q1 = *(const bf16x8*)&Qbh[(size_t)(qrow0 + ln)*HD + 32 + lg*8];

    f32x4 o[4] = {};
    float m = -1e30f, lsum = 0.f;

    auto epilogue = [&](int qr0) {
        const int bb = bh >> 4;
        const int h  = bh & 15;
        const float inv = 1.f / lsum;
        const size_t base = ((size_t)bb*SEQ + qr0 + ln)*D_MODEL + h*HD + lg*4;
        #pragma unroll
        for (int f = 0; f < 4; ++f) {
            uint2 w;
            w.x = pk2(o[f][0]*inv, o[f][1]*inv);
            w.y = pk2(o[f][2]*inv, o[f][3]*inv);
            *(uint2*)&AO[base + f*16] = w;
        }
    };

    stage(0, 0);

    for (int t = 0; t < nT; ++t) {
        __syncthreads();
        const int buf = t & 1;
        if (t + 1 < nT)
            stage(buf ^ 1, (t + 1 < nTA ? t + 1 : t + 1 - nTA) * 64);
        const int kt = (t < nTA ? t : t - nTA) * 64;

        f32x4 s[4];
        #pragma unroll
        for (int g = 0; g < 4; ++g) {
            bf16x8 ka = *(const bf16x8*)&Ks[buf][g*16 + ln][lg*8];
            bf16x8 kb = *(const bf16x8*)&Ks[buf][g*16 + ln][32 + lg*8];
            f32x4 sg = {};
            sg = __builtin_amdgcn_mfma_f32_16x16x32_bf16(ka, q0, sg, 0, 0, 0);
            sg = __builtin_amdgcn_mfma_f32_16x16x32_bf16(kb, q1, sg, 0, 0, 0);
            s[g] = sg;
        }

        const int qg = qrow0 + ln;
        const int kbase = kt + lg*4;
        float mx = -1e30f;
        #pragma unroll
        for (int g = 0; g < 4; ++g) {
            #pragma unroll
            for (int r = 0; r < 4; ++r) {
                float v = s[g][r] * 0.125f;
                v = (kbase + g*16 + r > qg) ? -1e30f : v;
                s[g][r] = v;
                mx = fmaxf(mx, v);
            }
        }
        mx = fmaxf(mx, __shfl_xor(mx, 16));
        mx = fmaxf(mx, __shfl_xor(mx, 32));

        if (__any(mx > m)) {
            const float mnew = fmaxf(m, mx);
            const float alpha = __expf(m - mnew);
            m = mnew;
            lsum *= alpha;
            #pragma unroll
            for (int f = 0; f < 4; ++f)
                #pragma unroll
                for (int r = 0; r < 4; ++r) o[f][r] *= alpha;
        }
        float ps = 0.f;
        #pragma unroll
        for (int g = 0; g < 4; ++g) {
            #pragma unroll
            for (int r = 0; r < 4; ++r) {
                const float e = __expf(s[g][r] - m);
                s[g][r] = e;
                ps += e;
            }
        }
        ps += __shfl_xor(ps, 16);
        ps += __shfl_xor(ps, 32);
        lsum += ps;

        #pragma unroll
        for (int g = 0; g < 4; ++g) {
            unsigned long long w =
                (unsigned long long)pk2(s[g][0], s[g][1]) |
                ((unsigned long long)pk2(s[g][2], s[g][3]) << 32);
            *(unsigned long long*)&Pl[wv][ln][g*16 + lg*4] = w;
        }
        bf16x8 pb0 = *(const bf16x8*)&Pl[wv][ln][lg*8];
        bf16x8 pb1 = *(const bf16x8*)&Pl[wv][ln][32 + lg*8];

        #pragma unroll
        for (int f = 0; f < 4; ++f) {
            bf16x8 v0 = *(const bf16x8*)&Vt[buf][f*16 + ln][lg*8];
            bf16x8 v1 = *(const bf16x8*)&Vt[buf][f*16 + ln][32 + lg*8];
            o[f] = __builtin_amdgcn_mfma_f32_16x16x32_bf16(v0, pb0, o[f], 0, 0, 0);
            o[f] = __builtin_amdgcn_mfma_f32_16x16x32_bf16(v1, pb1, o[f], 0, 0, 0);
        }

        if (t == nTA - 1) {
            epilogue(qrow0);
            qrow0 = qtB*64 + wv*16;
            q0 = *(const bf16x8*)&Qbh[(size_t)(qrow0 + ln)*HD + lg*8];
            q1 = *(const bf16x8*)&Qbh[(size_t)(qrow0 + ln)*HD + 32 + lg*8];
            m = -1e30f; lsum = 0.f;
            #pragma unroll
            for (int f = 0; f < 4; ++f)
                #pragma unroll
                for (int r = 0; r < 4; ++r) o[f][r] = 0.f;
        }
    }
    epilogue(qrow0);   // q-tile B
}

// ---------------------------------------------------------------------------
extern "C" void kernel_launch(void* const* d_in, const int* in_sizes, int n_in,
                              void* d_out, int out_size, void* d_ws, size_t ws_size,
                              hipStream_t stream)
{
    const float* x     = (const float*)d_in[0];   // (2,2048,1024)
    const float* w_qkv = (const float*)d_in[1];   // (1024,3072)
    const float* w_out = (const float*)d_in[2];   // (1024,1024)
    float* out = (float*)d_out;                   // (2,2048,1024)

    const size_t nX  = (size_t)BATCH*SEQ*D_MODEL;      // 4 Mi
    const size_t nWq = (size_t)D_MODEL*3*D_MODEL;      // 3 Mi
    const size_t nWo = (size_t)D_MODEL*D_MODEL;        // 1 Mi
    const size_t per = (size_t)BH * SEQ * HD;          // 4 Mi

    unsigned short* Xb   = (unsigned short*)d_ws;      // bf16 x (M x K)
    unsigned short* WqT  = Xb   + nX;                  // bf16 w_qkv^T (3072 x 1024)
    unsigned short* WoT  = WqT  + nWq;                 // bf16 w_out^T (1024 x 1024)
    unsigned short* Qb   = WoT  + nWo;
    unsigned short* Kb   = Qb + per;
    unsigned short* Vb   = Kb + per;
    unsigned short* AOb  = Vb + per;                   // bf16 (B,S,D)

    cvt_kernel<<<1024, 256, 0, stream>>>(x, Xb, (int)(nX/8));
    // weight transposes: grid (96 wqkv-tiles + 32 wout-tiles, 32 k-tiles)
    cvt_tr_kernel<<<dim3(128, 32), 256, 0, stream>>>(w_qkv, w_out, WqT, WoT);

    // qkv projection: grid = (N/128, M/128) = (24, 32)
    gemm_bf16_kernel<3*D_MODEL, true><<<dim3(24, 32), 256, 0, stream>>>(
        Xb, WqT, Qb, Kb, Vb, nullptr);
    // causal attention: paired q-tiles, grid = (16, 32) = 512 blocks
    attn_kernel<<<dim3(16, BH), 256, 0, stream>>>(Qb, Kb, Vb, AOb);
    // output projection: grid = (N/128, M/128) = (8, 32)
    gemm_bf16_kernel<D_MODEL, false><<<dim3(8, 32), 256, 0, stream>>>(
        AOb, WoT, nullptr, nullptr, nullptr, out);
}

// Round 16
// 124.779 us; speedup vs baseline: 12.8092x; 1.0900x over previous
//
#include <hip/hip_runtime.h>
#include <hip/hip_bf16.h>
#include <cstddef>

#define D_MODEL 1024
#define NHEAD   16
#define HD      64
#define BATCH   2
#define SEQ     2048
#define BH      (BATCH*NHEAD)   // 32

typedef short bf16x8 __attribute__((ext_vector_type(8)));
typedef float f32x4  __attribute__((ext_vector_type(4)));

static __device__ __forceinline__ unsigned short f2bf(float f) {
    __hip_bfloat16 h = __float2bfloat16(f);   // RNE
    return __builtin_bit_cast(unsigned short, h);
}
static __device__ __forceinline__ unsigned int pk2(float a, float b) {
    return (unsigned int)f2bf(a) | ((unsigned int)f2bf(b) << 16);
}

// global -> LDS async DMA, 16B per lane: LDS dest = uniform base + lane*16.
#define GLD16(gp, lp) __builtin_amdgcn_global_load_lds( \
    (const __attribute__((address_space(1))) unsigned int*)(gp), \
    (__attribute__((address_space(3))) unsigned int*)(lp), 16, 0, 0)

// ---------------------------------------------------------------------------
// K0a: fp32 -> bf16 linear (x only). 8 elems/thread, grid-stride.
// ---------------------------------------------------------------------------
__global__ __launch_bounds__(256) void cvt_kernel(
    const float* __restrict__ src, unsigned short* __restrict__ dst, int n8)
{
    const int stride = gridDim.x * blockDim.x;
    for (int i = blockIdx.x*blockDim.x + threadIdx.x; i < n8; i += stride) {
        const float4 a = ((const float4*)src)[i*2];
        const float4 b = ((const float4*)src)[i*2+1];
        uint4 w;
        w.x = pk2(a.x, a.y); w.y = pk2(a.z, a.w);
        w.z = pk2(b.x, b.y); w.w = pk2(b.z, b.w);
        ((uint4*)dst)[i] = w;
    }
}

// ---------------------------------------------------------------------------
// K0b: fp32 (K x N) -> bf16 TRANSPOSED (N x K) for both weights, one launch.
// ---------------------------------------------------------------------------
__global__ __launch_bounds__(256) void cvt_tr_kernel(
    const float* __restrict__ Wq, const float* __restrict__ Wo,
    unsigned short* __restrict__ WqT, unsigned short* __restrict__ WoT)
{
    __shared__ float T[32][33];
    const int tid = threadIdx.x;
    const int bx  = blockIdx.x;       // n-tile
    const int k0  = blockIdx.y * 32;  // k-tile
    const float* W; unsigned short* WT; int N, n0;
    if (bx < 96) { W = Wq; WT = WqT; N = 3072; n0 = bx*32; }
    else         { W = Wo; WT = WoT; N = 1024; n0 = (bx-96)*32; }
    const int r  = tid >> 3;          // 0..31
    const int cg = tid & 7;           // 0..7
    float4 v = *(const float4*)&W[(size_t)(k0 + r)*N + n0 + cg*4];
    T[r][cg*4+0] = v.x; T[r][cg*4+1] = v.y;
    T[r][cg*4+2] = v.z; T[r][cg*4+3] = v.w;
    __syncthreads();
    uint2 w;
    w.x = pk2(T[cg*4+0][r], T[cg*4+1][r]);
    w.y = pk2(T[cg*4+2][r], T[cg*4+3][r]);
    *(uint2*)&WT[(size_t)(n0 + r)*1024 + k0 + cg*4] = w;
}

// ---------------------------------------------------------------------------
// K1/K3 v2: bf16 MFMA GEMM with global_load_lds staging. Unchanged (R15,
// bit-exact, 24+8 blocks).
// ---------------------------------------------------------------------------
template<int NN, bool QKV>
__global__ __launch_bounds__(256, 2) void gemm_bf16_kernel(
    const unsigned short* __restrict__ A, const unsigned short* __restrict__ BT,
    unsigned short* __restrict__ Qo, unsigned short* __restrict__ Ko,
    unsigned short* __restrict__ Vo, float* __restrict__ Cf)
{
    __shared__ __align__(16) unsigned short As[128*32];
    __shared__ __align__(16) unsigned short Bs[128*32];

    const int tid  = threadIdx.x;
    const int wv   = tid >> 6;
    const int l    = tid & 63;
    const int ln   = l & 15;
    const int lg   = l >> 4;
    const int wrow = (wv >> 1) * 64;
    const int wcol = (wv & 1) * 64;
    const int mtile = blockIdx.y * 128;
    const int ntile = blockIdx.x * 128;

    const int c0 = wv*128 + l;
    const int c1 = c0 + 64;
    const int r0 = c0 >> 2, ks0 = ((c0 & 3) ^ ((r0 + (r0 >> 2)) & 3)) * 8;
    const int r1 = c1 >> 2, ks1 = ((c1 & 3) ^ ((r1 + (r1 >> 2)) & 3)) * 8;
    const size_t gA0 = (size_t)(mtile + r0)*1024 + ks0;
    const size_t gA1 = (size_t)(mtile + r1)*1024 + ks1;
    const size_t gB0 = (size_t)(ntile + r0)*1024 + ks0;
    const size_t gB1 = (size_t)(ntile + r1)*1024 + ks1;
    unsigned short* lA0 = &As[(wv*128     ) * 8];
    unsigned short* lA1 = &As[(wv*128 + 64) * 8];
    unsigned short* lB0 = &Bs[(wv*128     ) * 8];
    unsigned short* lB1 = &Bs[(wv*128 + 64) * 8];

    const int sw = ((lg ^ ((ln + (ln >> 2)) & 3))) * 8;

    f32x4 acc[4][4] = {};

    for (int kb = 0; kb < 32; ++kb) {
        const int koff = kb * 32;
        GLD16(A  + gA0 + koff, lA0);
        GLD16(A  + gA1 + koff, lA1);
        GLD16(BT + gB0 + koff, lB0);
        GLD16(BT + gB1 + koff, lB1);
        __syncthreads();
        bf16x8 af[4], bf[4];
        #pragma unroll
        for (int i = 0; i < 4; ++i)
            af[i] = *(const bf16x8*)&As[(wrow + i*16 + ln)*32 + sw];
        #pragma unroll
        for (int j = 0; j < 4; ++j)
            bf[j] = *(const bf16x8*)&Bs[(wcol + j*16 + ln)*32 + sw];
        #pragma unroll
        for (int i = 0; i < 4; ++i)
            #pragma unroll
            for (int j = 0; j < 4; ++j)
                acc[i][j] = __builtin_amdgcn_mfma_f32_16x16x32_bf16(af[i], bf[j], acc[i][j], 0, 0, 0);
        __syncthreads();
    }

    #pragma unroll
    for (int i = 0; i < 4; ++i) {
        #pragma unroll
        for (int r = 0; r < 4; ++r) {
            const int mm = mtile + wrow + i*16 + lg*4 + r;
            if constexpr (QKV) {
                const int bb = mm >> 11;
                const int ss = mm & 2047;
                #pragma unroll
                for (int j = 0; j < 4; ++j) {
                    const int cb  = ntile + wcol + j*16 + ln;
                    const int wch = cb >> 10;
                    const int rem = cb & 1023;
                    const int h   = rem >> 6;
                    const int dd  = rem & 63;
                    unsigned short* dstBase = (wch == 0) ? Qo : (wch == 1) ? Ko : Vo;
                    dstBase[((size_t)(bb*NHEAD + h)*SEQ + ss)*HD + dd] = f2bf(acc[i][j][r]);
                }
            } else {
                #pragma unroll
                for (int j = 0; j < 4; ++j) {
                    const int cb = ntile + wcol + j*16 + ln;
                    Cf[(size_t)mm*NN + cb] = acc[i][j][r];
                }
            }
        }
    }
}

// ---------------------------------------------------------------------------
// K2 v10: swapped-QK^T flash attention + T14 async-STAGE split.
// v9 staged tile t+1 (global load -> immediate LDS write) between the
// barrier and compute: the vmcnt wait sat ON the critical path each of the
// 33 tiles. v10 splits: LOADS for tile t+2 are issued right after the LDS
// write of t+1 (end of compute t), so they hide under the whole compute
// phase of t+1; the vmcnt + ds_write lands after compute, just before the
// barrier that publishes the buffer. +16 VGPR in-flight regs (~85 total,
// cap 128 at (256,2)). Everything else identical to v9 (71 us, .0156).
// ---------------------------------------------------------------------------
__global__ __launch_bounds__(256, 2) void attn_kernel(
    const unsigned short* __restrict__ Qb, const unsigned short* __restrict__ Kb,
    const unsigned short* __restrict__ Vb, unsigned short* __restrict__ AO)
{
    __shared__ __align__(16) unsigned short Ks[2][64][72];  // keys x dims(+pad)
    __shared__ __align__(16) unsigned short Vt[2][64][72];  // dims x keys(+pad)
    __shared__ __align__(16) unsigned short Pl[4][16][76];  // per-wave P^T

    const int tid = threadIdx.x;
    const int wv  = tid >> 6;
    const int l   = tid & 63;
    const int ln  = l & 15;
    const int lg  = l >> 4;
    const int bh  = blockIdx.y;
    const int bx  = blockIdx.x;          // 0..15
    const int qtA = 31 - bx;
    const int qtB = bx;
    const int nTA = qtA + 1;
    const int nT  = nTA + qtB + 1;       // 33 always

    const unsigned short* Qbh = Qb + (size_t)bh*SEQ*HD;
    const unsigned short* Kbh = Kb + (size_t)bh*SEQ*HD;
    const unsigned short* Vbh = Vb + (size_t)bh*SEQ*HD;

    const int s_kl = tid >> 3;
    const int s_d0 = (tid & 7) << 3;
    const int s_dg = tid >> 4;
    const int s_kp = (tid & 15) << 1;

    auto ktOf = [&](int t) { return (t < nTA ? t : t - nTA) * 64; };

    // T14 split: global->regs (issue early) vs regs->LDS (write late)
    uint4 rk0, rk1;
    uint2 rva0, rvb0, rva1, rvb1;
    auto load_tile = [&](int kt) {
        rk0  = *(const uint4*)&Kbh[(size_t)(kt + s_kl     )*HD + s_d0];
        rk1  = *(const uint4*)&Kbh[(size_t)(kt + s_kl + 32)*HD + s_d0];
        rva0 = *(const uint2*)&Vbh[(size_t)(kt + s_kp     )*HD + s_dg*4];
        rvb0 = *(const uint2*)&Vbh[(size_t)(kt + s_kp + 1 )*HD + s_dg*4];
        rva1 = *(const uint2*)&Vbh[(size_t)(kt + s_kp + 32)*HD + s_dg*4];
        rvb1 = *(const uint2*)&Vbh[(size_t)(kt + s_kp + 33)*HD + s_dg*4];
    };
    auto write_tile = [&](int nb) {
        *(uint4*)&Ks[nb][s_kl     ][s_d0] = rk0;
        *(uint4*)&Ks[nb][s_kl + 32][s_d0] = rk1;
        *(unsigned int*)&Vt[nb][s_dg*4+0][s_kp]    = (rva0.x & 0xffffu) | (rvb0.x << 16);
        *(unsigned int*)&Vt[nb][s_dg*4+1][s_kp]    = (rva0.x >> 16)     | (rvb0.x & 0xffff0000u);
        *(unsigned int*)&Vt[nb][s_dg*4+2][s_kp]    = (rva0.y & 0xffffu) | (rvb0.y << 16);
        *(unsigned int*)&Vt[nb][s_dg*4+3][s_kp]    = (rva0.y >> 16)     | (rvb0.y & 0xffff0000u);
        *(unsigned int*)&Vt[nb][s_dg*4+0][s_kp+32] = (rva1.x & 0xffffu) | (rvb1.x << 16);
        *(unsigned int*)&Vt[nb][s_dg*4+1][s_kp+32] = (rva1.x >> 16)     | (rvb1.x & 0xffff0000u);
        *(unsigned int*)&Vt[nb][s_dg*4+2][s_kp+32] = (rva1.y & 0xffffu) | (rvb1.y << 16);
        *(unsigned int*)&Vt[nb][s_dg*4+3][s_kp+32] = (rva1.y >> 16)     | (rvb1.y & 0xffff0000u);
    };

    int qrow0 = qtA*64 + wv*16;
    bf16x8 q0 = *(const bf16x8*)&Qbh[(size_t)(qrow0 + ln)*HD + lg*8];
    bf16x8 q1 = *(const bf16x8*)&Qbh[(size_t)(qrow0 + ln)*HD + 32 + lg*8];

    f32x4 o[4] = {};
    float m = -1e30f, lsum = 0.f;

    auto epilogue = [&](int qr0) {
        const int bb = bh >> 4;
        const int h  = bh & 15;
        const float inv = 1.f / lsum;
        const size_t base = ((size_t)bb*SEQ + qr0 + ln)*D_MODEL + h*HD + lg*4;
        #pragma unroll
        for (int f = 0; f < 4; ++f) {
            uint2 w;
            w.x = pk2(o[f][0]*inv, o[f][1]*inv);
            w.y = pk2(o[f][2]*inv, o[f][3]*inv);
            *(uint2*)&AO[base + f*16] = w;
        }
    };

    // prologue: tile 0 staged synchronously; tile 1 loads issued early
    load_tile(0);
    write_tile(0);
    if (nT > 1) load_tile(ktOf(1));

    for (int t = 0; t < nT; ++t) {
        __syncthreads();                     // publishes buf[t&1]
        const int buf = t & 1;
        const int kt = ktOf(t);

        // ---- QK^T swapped: S^T(64keys x 16q)
        f32x4 s[4];
        #pragma unroll
        for (int g = 0; g < 4; ++g) {
            bf16x8 ka = *(const bf16x8*)&Ks[buf][g*16 + ln][lg*8];
            bf16x8 kb = *(const bf16x8*)&Ks[buf][g*16 + ln][32 + lg*8];
            f32x4 sg = {};
            sg = __builtin_amdgcn_mfma_f32_16x16x32_bf16(ka, q0, sg, 0, 0, 0);
            sg = __builtin_amdgcn_mfma_f32_16x16x32_bf16(kb, q1, sg, 0, 0, 0);
            s[g] = sg;
        }

        const int qg = qrow0 + ln;
        const int kbase = kt + lg*4;
        float mx = -1e30f;
        #pragma unroll
        for (int g = 0; g < 4; ++g) {
            #pragma unroll
            for (int r = 0; r < 4; ++r) {
                float v = s[g][r] * 0.125f;
                v = (kbase + g*16 + r > qg) ? -1e30f : v;
                s[g][r] = v;
                mx = fmaxf(mx, v);
            }
        }
        mx = fmaxf(mx, __shfl_xor(mx, 16));
        mx = fmaxf(mx, __shfl_xor(mx, 32));

        if (__any(mx > m)) {
            const float mnew = fmaxf(m, mx);
            const float alpha = __expf(m - mnew);
            m = mnew;
            lsum *= alpha;
            #pragma unroll
            for (int f = 0; f < 4; ++f)
                #pragma unroll
                for (int r = 0; r < 4; ++r) o[f][r] *= alpha;
        }
        float ps = 0.f;
        #pragma unroll
        for (int g = 0; g < 4; ++g) {
            #pragma unroll
            for (int r = 0; r < 4; ++r) {
                const float e = __expf(s[g][r] - m);
                s[g][r] = e;
                ps += e;
            }
        }
        ps += __shfl_xor(ps, 16);
        ps += __shfl_xor(ps, 32);
        lsum += ps;

        #pragma unroll
        for (int g = 0; g < 4; ++g) {
            unsigned long long w =
                (unsigned long long)pk2(s[g][0], s[g][1]) |
                ((unsigned long long)pk2(s[g][2], s[g][3]) << 32);
            *(unsigned long long*)&Pl[wv][ln][g*16 + lg*4] = w;
        }
        bf16x8 pb0 = *(const bf16x8*)&Pl[wv][ln][lg*8];
        bf16x8 pb1 = *(const bf16x8*)&Pl[wv][ln][32 + lg*8];

        #pragma unroll
        for (int f = 0; f < 4; ++f) {
            bf16x8 v0 = *(const bf16x8*)&Vt[buf][f*16 + ln][lg*8];
            bf16x8 v1 = *(const bf16x8*)&Vt[buf][f*16 + ln][32 + lg*8];
            o[f] = __builtin_amdgcn_mfma_f32_16x16x32_bf16(v0, pb0, o[f], 0, 0, 0);
            o[f] = __builtin_amdgcn_mfma_f32_16x16x32_bf16(v1, pb1, o[f], 0, 0, 0);
        }

        // ---- late stage write for t+1 (vmcnt hidden under compute above),
        // then issue loads for t+2 (hide under compute of t+1)
        if (t + 1 < nT) {
            write_tile(buf ^ 1);
            if (t + 2 < nT) load_tile(ktOf(t + 2));
        }

        // ---- phase boundary: flush q-tile A, reset for q-tile B
        if (t == nTA - 1) {
            epilogue(qrow0);
            qrow0 = qtB*64 + wv*16;
            q0 = *(const bf16x8*)&Qbh[(size_t)(qrow0 + ln)*HD + lg*8];
            q1 = *(const bf16x8*)&Qbh[(size_t)(qrow0 + ln)*HD + 32 + lg*8];
            m = -1e30f; lsum = 0.f;
            #pragma unroll
            for (int f = 0; f < 4; ++f)
                #pragma unroll
                for (int r = 0; r < 4; ++r) o[f][r] = 0.f;
        }
    }
    epilogue(qrow0);   // q-tile B
}

// ---------------------------------------------------------------------------
extern "C" void kernel_launch(void* const* d_in, const int* in_sizes, int n_in,
                              void* d_out, int out_size, void* d_ws, size_t ws_size,
                              hipStream_t stream)
{
    const float* x     = (const float*)d_in[0];   // (2,2048,1024)
    const float* w_qkv = (const float*)d_in[1];   // (1024,3072)
    const float* w_out = (const float*)d_in[2];   // (1024,1024)
    float* out = (float*)d_out;                   // (2,2048,1024)

    const size_t nX  = (size_t)BATCH*SEQ*D_MODEL;      // 4 Mi
    const size_t nWq = (size_t)D_MODEL*3*D_MODEL;      // 3 Mi
    const size_t nWo = (size_t)D_MODEL*D_MODEL;        // 1 Mi
    const size_t per = (size_t)BH * SEQ * HD;          // 4 Mi

    unsigned short* Xb   = (unsigned short*)d_ws;      // bf16 x (M x K)
    unsigned short* WqT  = Xb   + nX;                  // bf16 w_qkv^T
    unsigned short* WoT  = WqT  + nWq;                 // bf16 w_out^T
    unsigned short* Qb   = WoT  + nWo;
    unsigned short* Kb   = Qb + per;
    unsigned short* Vb   = Kb + per;
    unsigned short* AOb  = Vb + per;                   // bf16 (B,S,D)

    cvt_kernel<<<1024, 256, 0, stream>>>(x, Xb, (int)(nX/8));
    cvt_tr_kernel<<<dim3(128, 32), 256, 0, stream>>>(w_qkv, w_out, WqT, WoT);

    gemm_bf16_kernel<3*D_MODEL, true><<<dim3(24, 32), 256, 0, stream>>>(
        Xb, WqT, Qb, Kb, Vb, nullptr);
    attn_kernel<<<dim3(16, BH), 256, 0, stream>>>(Qb, Kb, Vb, AOb);
    gemm_bf16_kernel<D_MODEL, false><<<dim3(8, 32), 256, 0, stream>>>(
        AOb, WoT, nullptr, nullptr, nullptr, out);
}